// Round 10
// baseline (751.031 us; speedup 1.0000x reference)
//
#include <hip/hip_runtime.h>
#include <hip/hip_cooperative_groups.h>
#include <math.h>

namespace cg = cooperative_groups;

typedef __attribute__((ext_vector_type(8))) short short8;
typedef __attribute__((ext_vector_type(4))) float floatx4;

__device__ __forceinline__ ushort f2b(float f) {
  unsigned u = __float_as_uint(f);
  unsigned r = u + 0x7FFFu + ((u >> 16) & 1u);
  return (ushort)(r >> 16);
}
__device__ __forceinline__ unsigned encf(float f) {
  unsigned u = __float_as_uint(f);
  return (u & 0x80000000u) ? ~u : (u | 0x80000000u);
}

struct Prm {
  const float *obs, *h0, *c0, *Wobs, *bobs, *Wih, *Whh, *bih, *bhh;
  const float *W1, *ai1, *aj1, *b1, *W2, *ai2, *aj2, *b2, *Wv, *bv, *Wa, *ba;
  float *out_logp, *out_value, *out_h, *out_c, *out_loss;
  ushort *Wihp, *Whhp, *WobsT, *W1T, *W2T, *WaTe, *wab1, *wab2;
  float *bias_ext, *bias12;
  ushort *enc_bf, *h_bf, *comm2_bf;
  float *h1, *comm1e, *h2b;
  float *part1, *part2, *pmn, *pmx;
  float *ci1, *cj1; unsigned *skey1; float *sc1; int *pm1;
  float *cku1, *ckv1, *ckus1, *ckvs1, *sufU1, *prefV1, *sufUs1, *prefVs1;
  float *ci2, *cj2; unsigned *skey2; float *sc2; int *pm2;
  float *cku2, *ckv2, *ckus2, *ckvs2, *sufU2, *prefV2, *sufUs2, *prefVs2;
  float *PUl, *PVl, *dUl, *dVl;
};

// ---------------- phase: prep ----------------
__device__ void ph_prep(const Prm& p, char* smem, int nb) {
  float* tile = (float*)smem;  // [32][33]
  const int tid = threadIdx.x;
  for (int bid = blockIdx.x; bid < 997; bid += nb) {
    if (bid < 512) {
      const int i = bid * 256 + tid;
      const int half = i >> 16;
      const int ii = i & 65535;
      const int pr = ii >> 6, k4 = ii & 63;
      const int orow = ((pr >> 4) & 3) * 256 + (pr >> 6) * 16 + (pr & 15);
      const float* s = half ? p.Whh : p.Wih;
      ushort* d = half ? p.Whhp : p.Wihp;
      const float4 v = *(const float4*)(s + (size_t)orow * 256 + k4 * 4);
      ushort4 o; o.x = f2b(v.x); o.y = f2b(v.y); o.z = f2b(v.z); o.w = f2b(v.w);
      *(ushort4*)(d + (size_t)pr * 256 + k4 * 4) = o;
    } else if (bid < 704) {
      const int t = bid - 512;
      const int mat = t >> 6, sub = t & 63;
      const float* in = mat == 0 ? p.Wobs : (mat == 1 ? p.W1 : p.W2);
      ushort* outp = mat == 0 ? p.WobsT : (mat == 1 ? p.W1T : p.W2T);
      const int c0 = (sub & 7) * 32, r0 = (sub >> 3) * 32;
      const int tx = tid & 31, ty = tid >> 5;
      #pragma unroll
      for (int q = 0; q < 32; q += 8)
        tile[(ty + q) * 33 + tx] = in[(size_t)(r0 + ty + q) * 256 + c0 + tx];
      __syncthreads();
      #pragma unroll
      for (int q = 0; q < 32; q += 8)
        outp[(size_t)(c0 + ty + q) * 256 + r0 + tx] = f2b(tile[tx * 33 + ty + q]);
      __syncthreads();
    } else if (bid < 965) {
      const int idx = (bid - 704) * 256 + tid;
      if (idx < 65536) {
        const int n = idx >> 9, k = idx & 511;
        const float v = n < 64 ? p.Wa[(size_t)k * 64 + n] : (n == 64 ? p.Wv[k] : 0.0f);
        p.WaTe[idx] = f2b(v);
      } else if (idx < 65536 + 128) {
        const int n = idx - 65536;
        p.bias_ext[n] = n < 64 ? p.ba[n] : (n == 64 ? p.bv[0] : 0.0f);
      } else if (idx < 65536 + 128 + 1024) {
        const int pc = idx - 65536 - 128;
        const int orow = ((pc >> 4) & 3) * 256 + (pc >> 6) * 16 + (pc & 15);
        p.bias12[pc] = p.bih[orow] + p.bhh[orow];
      }
    } else if (bid < 981) {
      const int c = bid - 965;
      const int k = tid;
      float val = 0.0f;
      if (c < 8) {
        const int h = c & 3;
        const float* av = (c < 4) ? p.ai1 : p.aj1;
        for (int g = 0; g < 64; ++g)
          val += p.W1[(size_t)k * 256 + h * 64 + g] * av[h * 64 + g];
      }
      p.wab1[c * 256 + k] = f2b(val);
    } else {
      const int c = bid - 981;
      const int k = tid;
      float val = 0.0f;
      if (c < 2) {
        const float* av = (c == 0) ? p.ai2 : p.aj2;
        for (int g = 0; g < 256; ++g)
          val += p.W2[(size_t)k * 256 + g] * av[g];
      }
      p.wab2[c * 256 + k] = f2b(val);
    }
  }
}

// ---------------- phase: enc GEMM ----------------
__device__ void ph_enc(const Prm& p, char* smem, int nb) {
  constexpr int LDT = 40;
  ushort* As = (ushort*)smem;
  ushort* Bs = As + 64 * LDT;
  const int tid = threadIdx.x;
  const int wave = tid >> 6, lane = tid & 63;
  const int wr = wave >> 1, wc = wave & 1;
  const int r = tid >> 2, kq = tid & 3;
  const int lm = lane & 15, lq = lane >> 4;
  for (int b = blockIdx.x; b < 256; b += nb) {
    const int m0 = (b >> 2) * 64, n0 = (b & 3) * 64;
    floatx4 acc[2][2] = {};
    for (int k0 = 0; k0 < 256; k0 += 32) {
      {
        const float* s = &p.obs[(size_t)(m0 + r) * 256 + k0 + kq * 8];
        const float4 a = *(const float4*)s;
        const float4 bb = *(const float4*)(s + 4);
        ushort4 o1, o2;
        o1.x = f2b(a.x); o1.y = f2b(a.y); o1.z = f2b(a.z); o1.w = f2b(a.w);
        o2.x = f2b(bb.x); o2.y = f2b(bb.y); o2.z = f2b(bb.z); o2.w = f2b(bb.w);
        *(ushort4*)&As[r * LDT + kq * 8] = o1;
        *(ushort4*)&As[r * LDT + kq * 8 + 4] = o2;
        *(float4*)&Bs[r * LDT + kq * 8] =
            *(const float4*)&p.WobsT[(size_t)(n0 + r) * 256 + k0 + kq * 8];
      }
      __syncthreads();
      short8 af[2], bfr[2];
      #pragma unroll
      for (int i = 0; i < 2; ++i)
        af[i] = *(const short8*)&As[(wr * 32 + i * 16 + lm) * LDT + lq * 8];
      #pragma unroll
      for (int j = 0; j < 2; ++j)
        bfr[j] = *(const short8*)&Bs[(wc * 32 + j * 16 + lm) * LDT + lq * 8];
      #pragma unroll
      for (int i = 0; i < 2; ++i)
        #pragma unroll
        for (int j = 0; j < 2; ++j)
          acc[i][j] = __builtin_amdgcn_mfma_f32_16x16x32_bf16(af[i], bfr[j], acc[i][j], 0, 0, 0);
      __syncthreads();
    }
    #pragma unroll
    for (int i = 0; i < 2; ++i)
      #pragma unroll
      for (int j = 0; j < 2; ++j) {
        const int col = n0 + wc * 32 + j * 16 + lm;
        const float badd = p.bobs[col];
        #pragma unroll
        for (int t = 0; t < 4; ++t) {
          const int row = m0 + wr * 32 + i * 16 + lq * 4 + t;
          p.enc_bf[(size_t)row * 256 + col] = f2b(acc[i][j][t] + badd);
        }
      }
  }
}

// ---------------- phase: gates GEMM + LSTM ----------------
__device__ void ph_gates(const Prm& p, char* smem, int nb) {
  constexpr int LDT = 40;
  ushort* As = (ushort*)smem;
  ushort* Bs = As + 128 * LDT;
  float* sred = (float*)(smem + 20480);
  const int tid = threadIdx.x;
  const int wave = tid >> 6, lane = tid & 63;
  const int wr = wave >> 1, wc = wave & 1;
  const int r = tid >> 2, kq = tid & 3;
  const int lm = lane & 15, lq = lane >> 4;
  for (int b = blockIdx.x; b < 256; b += nb) {
    const int bx = b & 7, by = b >> 3;
    const int m0 = by * 128, n0 = bx * 128;
    floatx4 acc[4][4] = {};
    for (int k0 = 0; k0 < 512; k0 += 32) {
      const ushort* B = (k0 < 256) ? p.Wihp : p.Whhp;
      const int kk = (k0 < 256) ? k0 : k0 - 256;
      if (k0 < 256) {
        #pragma unroll
        for (int q = 0; q < 2; ++q) {
          const int rr = r + q * 64;
          *(float4*)&As[rr * LDT + kq * 8] =
              *(const float4*)&p.enc_bf[(size_t)(m0 + rr) * 256 + kk + kq * 8];
        }
      } else {
        #pragma unroll
        for (int q = 0; q < 2; ++q) {
          const int rr = r + q * 64;
          const float* s = &p.h0[(size_t)(m0 + rr) * 256 + kk + kq * 8];
          const float4 a = *(const float4*)s;
          const float4 bb = *(const float4*)(s + 4);
          ushort4 o1, o2;
          o1.x = f2b(a.x); o1.y = f2b(a.y); o1.z = f2b(a.z); o1.w = f2b(a.w);
          o2.x = f2b(bb.x); o2.y = f2b(bb.y); o2.z = f2b(bb.z); o2.w = f2b(bb.w);
          *(ushort4*)&As[rr * LDT + kq * 8] = o1;
          *(ushort4*)&As[rr * LDT + kq * 8 + 4] = o2;
        }
      }
      #pragma unroll
      for (int q = 0; q < 2; ++q) {
        const int rr = r + q * 64;
        *(float4*)&Bs[rr * LDT + kq * 8] =
            *(const float4*)&B[(size_t)(n0 + rr) * 256 + kk + kq * 8];
      }
      __syncthreads();
      short8 af[4], bfr[4];
      #pragma unroll
      for (int i = 0; i < 4; ++i)
        af[i] = *(const short8*)&As[(wr * 64 + i * 16 + lm) * LDT + lq * 8];
      #pragma unroll
      for (int j = 0; j < 4; ++j)
        bfr[j] = *(const short8*)&Bs[(wc * 64 + j * 16 + lm) * LDT + lq * 8];
      #pragma unroll
      for (int i = 0; i < 4; ++i)
        #pragma unroll
        for (int j = 0; j < 4; ++j)
          acc[i][j] = __builtin_amdgcn_mfma_f32_16x16x32_bf16(af[i], bfr[j], acc[i][j], 0, 0, 0);
      __syncthreads();
    }
    const int d = (bx * 2 + wc) * 16 + lm;
    float b4[4];
    #pragma unroll
    for (int j = 0; j < 4; ++j) b4[j] = p.bias12[n0 + wc * 64 + j * 16 + lm];
    float mnl = 3.0e38f, mxl = -3.0e38f;
    #pragma unroll
    for (int i = 0; i < 4; ++i) {
      #pragma unroll
      for (int t = 0; t < 4; ++t) {
        const int row = m0 + wr * 64 + i * 16 + lq * 4 + t;
        const size_t off = (size_t)row * 256 + d;
        const float gi = acc[i][0][t] + b4[0];
        const float gf = acc[i][1][t] + b4[1];
        const float gg = acc[i][2][t] + b4[2];
        const float go = acc[i][3][t] + b4[3];
        const float cc = p.c0[off];
        const float si = 1.0f / (1.0f + expf(-gi));
        const float sf = 1.0f / (1.0f + expf(-gf));
        const float so = 1.0f / (1.0f + expf(-go));
        const float c2 = sf * cc + si * tanhf(gg);
        const float h2 = so * tanhf(c2);
        p.out_h[off] = h2;
        p.out_c[off] = c2;
        p.h_bf[off] = f2b(h2);
        mnl = fminf(mnl, h2); mxl = fmaxf(mxl, h2);
      }
    }
    #pragma unroll
    for (int o = 32; o > 0; o >>= 1) {
      mnl = fminf(mnl, __shfl_xor(mnl, o));
      mxl = fmaxf(mxl, __shfl_xor(mxl, o));
    }
    if (lane == 0) { sred[wave] = mnl; sred[4 + wave] = mxl; }
    __syncthreads();
    if (tid == 0) {
      p.pmn[b] = fminf(fminf(sred[0], sred[1]), fminf(sred[2], sred[3]));
      p.pmx[b] = fmaxf(fmaxf(sred[4], sred[5]), fmaxf(sred[6], sred[7]));
    }
    __syncthreads();
  }
}

// ---------------- phase: GAT features + fused quant ----------------
__device__ void ph_gatfeat(const Prm& p, char* smem, int nb, int HN,
                           const float* Af32, const ushort* WT, const ushort* wab,
                           const float* pmn, const float* pmx, int np, float* part,
                           float* hout, float* ci, float* cj) {
  constexpr int LDT = 40;
  ushort* As = (ushort*)smem;
  ushort* Bs = As + 64 * LDT;
  float* sred = (float*)(smem + 10240);
  float* s_sz = sred + 8;
  const int tid = threadIdx.x;
  const int wave = tid >> 6, lane = tid & 63;
  const int lm = lane & 15, lq = lane >> 4;
  const int r = tid >> 2, kq = tid & 3;
  {
    float mn = 3.0e38f, mx = -3.0e38f;
    for (int i = tid; i < np; i += 256) { mn = fminf(mn, pmn[i]); mx = fmaxf(mx, pmx[i]); }
    #pragma unroll
    for (int o = 32; o > 0; o >>= 1) {
      mn = fminf(mn, __shfl_xor(mn, o)); mx = fmaxf(mx, __shfl_xor(mx, o));
    }
    if (lane == 0) { sred[wave] = mn; sred[4 + wave] = mx; }
    __syncthreads();
    if (tid == 0) {
      float bmn = fminf(fminf(sred[0], sred[1]), fminf(sred[2], sred[3]));
      float bmx = fmaxf(fmaxf(sred[4], sred[5]), fmaxf(sred[6], sred[7]));
      if (bmn == bmx) { bmn -= 0.01f; bmx += 0.01f; }
      const float sc = (bmx - bmn) / 255.0f;
      s_sz[0] = sc; s_sz[1] = rintf(-bmn / sc);
    }
    __syncthreads();
  }
  const float scale = s_sz[0], zp = s_sz[1];
  for (int bid = blockIdx.x; bid < 320; bid += nb) {
    float lsum = 0.0f;
    auto qz = [&](float t) -> ushort {
      const float qq = fminf(fmaxf(rintf(t / scale + zp), 0.0f), 255.0f);
      const float dq = (qq - zp) * scale;
      lsum += log2f(510.0f * fabsf(dq) + 1.0f);
      return f2b(dq);
    };
    if (bid < 256) {
      const int bx = bid & 3, by = bid >> 2;
      const int m0 = by * 64, n0 = bx * 64;
      const int wr = wave >> 1, wc = wave & 1;
      floatx4 acc[2][2] = {};
      for (int k0 = 0; k0 < 256; k0 += 32) {
        {
          const float* s = &Af32[(size_t)(m0 + r) * 256 + k0 + kq * 8];
          const float4 a = *(const float4*)s;
          const float4 bb = *(const float4*)(s + 4);
          ushort4 o1, o2;
          o1.x = qz(a.x); o1.y = qz(a.y); o1.z = qz(a.z); o1.w = qz(a.w);
          o2.x = qz(bb.x); o2.y = qz(bb.y); o2.z = qz(bb.z); o2.w = qz(bb.w);
          *(ushort4*)&As[r * LDT + kq * 8] = o1;
          *(ushort4*)&As[r * LDT + kq * 8 + 4] = o2;
        }
        *(float4*)&Bs[r * LDT + kq * 8] =
            *(const float4*)&WT[(size_t)(n0 + r) * 256 + k0 + kq * 8];
        __syncthreads();
        short8 af[2], bfr[2];
        #pragma unroll
        for (int i = 0; i < 2; ++i)
          af[i] = *(const short8*)&As[(wr * 32 + i * 16 + lm) * LDT + lq * 8];
        #pragma unroll
        for (int j = 0; j < 2; ++j)
          bfr[j] = *(const short8*)&Bs[(wc * 32 + j * 16 + lm) * LDT + lq * 8];
        #pragma unroll
        for (int i = 0; i < 2; ++i)
          #pragma unroll
          for (int j = 0; j < 2; ++j)
            acc[i][j] = __builtin_amdgcn_mfma_f32_16x16x32_bf16(af[i], bfr[j], acc[i][j], 0, 0, 0);
        __syncthreads();
      }
      #pragma unroll
      for (int i = 0; i < 2; ++i)
        #pragma unroll
        for (int j = 0; j < 2; ++j) {
          const int col = n0 + wc * 32 + j * 16 + lm;
          #pragma unroll
          for (int t = 0; t < 4; ++t) {
            const int row = m0 + wr * 32 + i * 16 + lq * 4 + t;
            hout[(size_t)row * 256 + col] = acc[i][j][t];
          }
        }
      if (bx == 0) {
        #pragma unroll
        for (int o = 32; o > 0; o >>= 1) lsum += __shfl_xor(lsum, o);
        if (lane == 0) sred[wave] = lsum;
        __syncthreads();
        if (tid == 0) part[by] = sred[0] + sred[1] + sred[2] + sred[3];
      }
      __syncthreads();
    } else {
      const int m0 = (bid - 256) * 64;
      floatx4 acc = {0.f, 0.f, 0.f, 0.f};
      for (int k0 = 0; k0 < 256; k0 += 32) {
        {
          const float* s = &Af32[(size_t)(m0 + r) * 256 + k0 + kq * 8];
          const float4 a = *(const float4*)s;
          const float4 bb = *(const float4*)(s + 4);
          ushort4 o1, o2;
          o1.x = qz(a.x); o1.y = qz(a.y); o1.z = qz(a.z); o1.w = qz(a.w);
          o2.x = qz(bb.x); o2.y = qz(bb.y); o2.z = qz(bb.z); o2.w = qz(bb.w);
          *(ushort4*)&As[r * LDT + kq * 8] = o1;
          *(ushort4*)&As[r * LDT + kq * 8 + 4] = o2;
        }
        if (r < 16)
          *(float4*)&Bs[r * LDT + kq * 8] =
              *(const float4*)&wab[(size_t)r * 256 + k0 + kq * 8];
        __syncthreads();
        const short8 af = *(const short8*)&As[(wave * 16 + lm) * LDT + lq * 8];
        const short8 bf = *(const short8*)&Bs[lm * LDT + lq * 8];
        acc = __builtin_amdgcn_mfma_f32_16x16x32_bf16(af, bf, acc, 0, 0, 0);
        __syncthreads();
      }
      #pragma unroll
      for (int t = 0; t < 4; ++t) {
        const int row = m0 + wave * 16 + lq * 4 + t;
        if (lm < HN) ci[lm * 4096 + row] = acc[t];
        else if (lm < 2 * HN) cj[(lm - HN) * 4096 + row] = acc[t];
      }
      __syncthreads();
    }
  }
}

// ---------------- phase: rank sort (256-thread) ----------------
__device__ void ph_sort(const Prm& p, char* smem, int nb,
                        const float* c, unsigned* skey, float* sc, int* pm, int nseg) {
  unsigned* lk = (unsigned*)smem;          // 4096
  int* scnt = (int*)(lk + 4096);           // [4][64]
  const int tid = threadIdx.x;
  const int lane = tid & 63, kg = tid >> 6;
  for (int item = blockIdx.x; item < nseg; item += nb) {
    const int head = item >> 6, seg = item & 63;
    const float* ch = c + head * 4096;
    for (int idx = tid; idx < 4096; idx += 256)
      lk[idx] = (encf(ch[idx]) & 0xFFFFF000u) | (unsigned)idx;
    __syncthreads();
    const unsigned my = lk[seg * 64 + lane];
    int cnt = 0;
    const uint4* lk4 = (const uint4*)lk;
    const int k40 = kg * 256;
    #pragma unroll 8
    for (int k4 = k40; k4 < k40 + 256; ++k4) {
      const uint4 kv = lk4[k4];
      cnt += (kv.x < my ? 1 : 0) + (kv.y < my ? 1 : 0)
           + (kv.z < my ? 1 : 0) + (kv.w < my ? 1 : 0);
    }
    scnt[kg * 64 + lane] = cnt;
    __syncthreads();
    if (tid < 64) {
      int rank = scnt[tid] + scnt[64 + tid] + scnt[128 + tid] + scnt[192 + tid];
      const unsigned kk = lk[seg * 64 + tid];
      const int jj = (int)(kk & 0xFFFu);
      skey[head * 4096 + rank] = kk;
      sc[head * 4096 + rank] = ch[jj];
      pm[head * 4096 + rank] = jj;
    }
    __syncthreads();
  }
}

// ---------------- phase: local scan GAT1 ----------------
__device__ void ph_scan1(const Prm& p, int nb) {
  const int tid = threadIdx.x;
  const int wave = tid >> 6, lane = tid & 63;
  if (wave >= 2) return;  // no barriers below
  for (int item = blockIdx.x; item < 256; item += nb) {
    const int head = item >> 6, chunk = item & 63;
    const float cmax = p.sc1[head * 4096 + 4095];
    const int base = head * 4096 + chunk * 64;
    const float cv = p.sc1[base + lane];
    const float u = expf(cv - cmax);
    const float v = expf(0.2f * (cv - cmax));
    const int myj = p.pm1[base + lane];
    const float* hrow = p.h1 + head * 64 + lane;
    if (wave == 0) {
      float iu = u, iv = v;
      #pragma unroll
      for (int o = 1; o < 64; o <<= 1) {
        const float tu = __shfl_up(iu, o), tv = __shfl_up(iv, o);
        if (lane >= o) { iu += tu; iv += tv; }
      }
      const float totU = __shfl(iu, 63), totV = __shfl(iv, 63);
      p.dVl[base + lane] = iv - v;
      p.dUl[base + lane] = totU - (iu - u);
      if (lane == 0) { p.ckus1[head * 64 + chunk] = totU; p.ckvs1[head * 64 + chunk] = totV; }
      float accV = 0.f;
      #pragma unroll 16
      for (int k = 0; k < 64; ++k) {
        const float vk = __shfl(v, k);
        const int j = __shfl(myj, k);
        p.PVl[(size_t)(base + k) * 64 + lane] = accV;
        accV += vk * hrow[(size_t)j * 256];
      }
      p.ckv1[(head * 64 + chunk) * 64 + lane] = accV;
    } else {
      float accU = 0.f;
      #pragma unroll 16
      for (int k = 63; k >= 0; --k) {
        const float uk = __shfl(u, k);
        const int j = __shfl(myj, k);
        accU += uk * hrow[(size_t)j * 256];
        p.PUl[(size_t)(base + k) * 64 + lane] = accU;
      }
      p.cku1[(head * 64 + chunk) * 64 + lane] = accU;
    }
  }
}

// ---------------- phase: local scan GAT2 ----------------
__device__ void ph_scan2(const Prm& p, char* smem, int nb) {
  float* su = (float*)smem;
  float* sv = su + 64;
  int* sj = (int*)(sv + 64);
  const int tid = threadIdx.x;
  const int wave = tid >> 6, lane = tid & 63;
  for (int item = blockIdx.x; item < 128; item += nb) {
    const int colgrp = item & 1, chunk = item >> 1;
    const float cmax = p.sc2[4095];
    const int base = chunk * 64;
    if (tid < 64) {
      const float cv = p.sc2[base + tid];
      const float u = expf(cv - cmax);
      const float v = expf(0.2f * (cv - cmax));
      su[tid] = u; sv[tid] = v; sj[tid] = p.pm2[base + tid];
      if (colgrp == 0) {
        float iu = u, iv = v;
        #pragma unroll
        for (int o = 1; o < 64; o <<= 1) {
          const float tu = __shfl_up(iu, o), tv = __shfl_up(iv, o);
          if (lane >= o) { iu += tu; iv += tv; }
        }
        const float totU = __shfl(iu, 63), totV = __shfl(iv, 63);
        p.dVl[base + lane] = iv - v;
        p.dUl[base + lane] = totU - (iu - u);
        if (lane == 0) { p.ckus2[chunk] = totU; p.ckvs2[chunk] = totV; }
      }
    }
    __syncthreads();
    const int col = colgrp * 128 + (wave & 1) * 64 + lane;
    if (wave < 2) {
      float accV = 0.f;
      #pragma unroll 16
      for (int k = 0; k < 64; ++k) {
        p.PVl[(size_t)(base + k) * 256 + col] = accV;
        accV += sv[k] * p.h2b[(size_t)sj[k] * 256 + col];
      }
      p.ckv2[chunk * 256 + col] = accV;
    } else {
      float accU = 0.f;
      #pragma unroll 16
      for (int k = 63; k >= 0; --k) {
        accU += su[k] * p.h2b[(size_t)sj[k] * 256 + col];
        p.PUl[(size_t)(base + k) * 256 + col] = accU;
      }
      p.cku2[chunk * 256 + col] = accU;
    }
    __syncthreads();
  }
}

// ---------------- phase: prefix arrays ----------------
__device__ void ph_prefix1(const Prm& p, int nb) {
  const int tid = threadIdx.x;
  if (tid >= 64) return;
  const int lane = tid;
  for (int head = blockIdx.x; head < 4; head += nb) {
    float acc = 0.f;
    for (int c = 0; c < 64; ++c) {
      p.prefV1[(head * 65 + c) * 64 + lane] = acc;
      acc += p.ckv1[(head * 64 + c) * 64 + lane];
    }
    p.prefV1[(head * 65 + 64) * 64 + lane] = acc;
    acc = 0.f;
    p.sufU1[(head * 65 + 64) * 64 + lane] = 0.f;
    for (int c = 63; c >= 0; --c) {
      acc += p.cku1[(head * 64 + c) * 64 + lane];
      p.sufU1[(head * 65 + c) * 64 + lane] = acc;
    }
    {
      const float vs = p.ckvs1[head * 64 + lane];
      const float us = p.ckus1[head * 64 + lane];
      float iv = vs, iu = us;
      #pragma unroll
      for (int o = 1; o < 64; o <<= 1) {
        const float tv = __shfl_up(iv, o), tu = __shfl_up(iu, o);
        if (lane >= o) { iv += tv; iu += tu; }
      }
      p.prefVs1[head * 65 + lane] = iv - vs;
      const float totU = __shfl(iu, 63);
      p.sufUs1[head * 65 + lane] = totU - iu + us;
      if (lane == 63) {
        p.prefVs1[head * 65 + 64] = iv;
        p.sufUs1[head * 65 + 64] = 0.f;
      }
    }
  }
}

__device__ void ph_prefix2(const Prm& p) {
  if (blockIdx.x != 0) return;
  const int col = threadIdx.x;
  const int lane = col & 63;
  float acc = 0.f;
  for (int c = 0; c < 64; ++c) {
    p.prefV2[c * 256 + col] = acc;
    acc += p.ckv2[c * 256 + col];
  }
  p.prefV2[64 * 256 + col] = acc;
  acc = 0.f;
  p.sufU2[64 * 256 + col] = 0.f;
  for (int c = 63; c >= 0; --c) {
    acc += p.cku2[c * 256 + col];
    p.sufU2[c * 256 + col] = acc;
  }
  if (col < 64) {
    const float vs = p.ckvs2[lane];
    const float us = p.ckus2[lane];
    float iv = vs, iu = us;
    #pragma unroll
    for (int o = 1; o < 64; o <<= 1) {
      const float tv = __shfl_up(iv, o), tu = __shfl_up(iu, o);
      if (lane >= o) { iv += tv; iu += tu; }
    }
    p.prefVs2[lane] = iv - vs;
    const float totU = __shfl(iu, 63);
    p.sufUs2[lane] = totU - iu + us;
    if (lane == 63) { p.prefVs2[64] = iv; p.sufUs2[64] = 0.f; }
  }
}

// ---------------- phase: combine1 ----------------
__device__ void ph_combine1(const Prm& p, char* smem, int nb) {
  float* csm = (float*)smem;  // [8]
  const int tid = threadIdx.x;
  const int head = tid >> 6, lane = tid & 63;
  for (int i = blockIdx.x; i < 4096; i += nb) {
    const unsigned* skh = p.skey1 + head * 4096;
    const float civ = p.ci1[head * 4096 + i];
    const float cmax = p.sc1[head * 4096 + 4095];
    const float sarg = civ + cmax;
    const float m = sarg > 0.f ? sarg : 0.2f * sarg;
    const float Af = expf(sarg - m);
    const float Bf = expf(0.2f * sarg - m);
    const unsigned tkey = (encf(-civ) & 0xFFFFF000u) | 0xFFFu;
    int lo = 0, hi = 4096;
    while (lo < hi) {
      const int mid = (lo + hi) >> 1;
      if (skh[mid] > tkey) hi = mid; else lo = mid + 1;
    }
    const int s = lo;
    float accP, accN, dP, dN;
    if (s == 4096) {
      accP = 0.f; dP = 0.f;
      accN = p.prefV1[(head * 65 + 64) * 64 + lane];
      dN = p.prefVs1[head * 65 + 64];
    } else {
      const int cs = s >> 6;
      accP = p.sufU1[(head * 65 + cs + 1) * 64 + lane] + p.PUl[(size_t)(head * 4096 + s) * 64 + lane];
      accN = p.prefV1[(head * 65 + cs) * 64 + lane] + p.PVl[(size_t)(head * 4096 + s) * 64 + lane];
      dP = p.sufUs1[head * 65 + cs + 1] + p.dUl[head * 4096 + s];
      dN = p.prefVs1[head * 65 + cs] + p.dVl[head * 4096 + s];
    }
    const float num = Af * accP + Bf * accN;
    const float den = Af * dP + Bf * dN;
    const float o = num / den + p.b1[head * 64 + lane];
    const float oe = o > 0.f ? o : expm1f(o);
    p.comm1e[(size_t)i * 256 + head * 64 + lane] = oe;
    float mn = oe, mx = oe;
    #pragma unroll
    for (int of = 32; of > 0; of >>= 1) {
      mn = fminf(mn, __shfl_xor(mn, of));
      mx = fmaxf(mx, __shfl_xor(mx, of));
    }
    if (lane == 0) { csm[head] = mn; csm[4 + head] = mx; }
    __syncthreads();
    if (tid == 0) {
      p.pmn[i] = fminf(fminf(csm[0], csm[1]), fminf(csm[2], csm[3]));
      p.pmx[i] = fmaxf(fmaxf(csm[4], csm[5]), fmaxf(csm[6], csm[7]));
    }
    __syncthreads();
  }
}

// ---------------- phase: combine2 ----------------
__device__ void ph_combine2(const Prm& p, int nb) {
  const int col = threadIdx.x;
  for (int i = blockIdx.x; i < 4096; i += nb) {
    const float civ = p.ci2[i];
    const float cmax = p.sc2[4095];
    const float sarg = civ + cmax;
    const float m = sarg > 0.f ? sarg : 0.2f * sarg;
    const float Af = expf(sarg - m);
    const float Bf = expf(0.2f * sarg - m);
    const unsigned tkey = (encf(-civ) & 0xFFFFF000u) | 0xFFFu;
    int lo = 0, hi = 4096;
    while (lo < hi) {
      const int mid = (lo + hi) >> 1;
      if (p.skey2[mid] > tkey) hi = mid; else lo = mid + 1;
    }
    const int s = lo;
    float accP, accN, dP, dN;
    if (s == 4096) {
      accP = 0.f; dP = 0.f;
      accN = p.prefV2[64 * 256 + col];
      dN = p.prefVs2[64];
    } else {
      const int cs = s >> 6;
      accP = p.sufU2[(cs + 1) * 256 + col] + p.PUl[(size_t)s * 256 + col];
      accN = p.prefV2[cs * 256 + col] + p.PVl[(size_t)s * 256 + col];
      dP = p.sufUs2[cs + 1] + p.dUl[s];
      dN = p.prefVs2[cs] + p.dVl[s];
    }
    const float num = Af * accP + Bf * accN;
    const float den = Af * dP + Bf * dN;
    p.comm2_bf[(size_t)i * 256 + col] = f2b(num / den + p.b2[col]);
  }
}

// ---------------- phase: heads ----------------
__device__ void ph_heads(const Prm& p, char* smem, int nb) {
  constexpr int LDT = 40;
  ushort* As = (ushort*)smem;                // 32*40
  ushort* Bs = As + 32 * LDT;                // 128*40
  float* lbuf = (float*)(smem + 2560 + 10240);  // [32][68]
  const int tid = threadIdx.x;
  const int wave = tid >> 6, lane = tid & 63;
  const int wr = wave >> 1, wc = wave & 1;
  const int lm = lane & 15, lq = lane >> 4;
  const int r = tid >> 2, kq = tid & 3;
  for (int item = blockIdx.x; item < 128; item += nb) {
    const int m0 = item * 32;
    floatx4 acc[4] = {};
    for (int k0 = 0; k0 < 512; k0 += 32) {
      const ushort* Asrc = (k0 < 256) ? p.h_bf : p.comm2_bf;
      const int kk = (k0 < 256) ? k0 : k0 - 256;
      if (tid < 128)
        *(float4*)&As[r * LDT + kq * 8] =
            *(const float4*)&Asrc[(size_t)(m0 + r) * 256 + kk + kq * 8];
      #pragma unroll
      for (int q = 0; q < 2; ++q) {
        const int rr = r + q * 64;
        *(float4*)&Bs[rr * LDT + kq * 8] =
            *(const float4*)&p.WaTe[(size_t)rr * 512 + k0 + kq * 8];
      }
      __syncthreads();
      const short8 af = *(const short8*)&As[(wr * 16 + lm) * LDT + lq * 8];
      short8 bfr[4];
      #pragma unroll
      for (int j = 0; j < 4; ++j)
        bfr[j] = *(const short8*)&Bs[(wc * 64 + j * 16 + lm) * LDT + lq * 8];
      #pragma unroll
      for (int j = 0; j < 4; ++j)
        acc[j] = __builtin_amdgcn_mfma_f32_16x16x32_bf16(af, bfr[j], acc[j], 0, 0, 0);
      __syncthreads();
    }
    #pragma unroll
    for (int j = 0; j < 4; ++j) {
      const int col = wc * 64 + j * 16 + lm;
      if (col < 65) {
        const float badd = p.bias_ext[col];
        #pragma unroll
        for (int t = 0; t < 4; ++t)
          lbuf[(wr * 16 + lq * 4 + t) * 68 + col] = acc[j][t] + badd;
      }
    }
    __syncthreads();
    for (int rr2 = 0; rr2 < 8; ++rr2) {
      const int row = wave * 8 + rr2;
      const float x = lbuf[row * 68 + lane];
      float mx = x;
      #pragma unroll
      for (int o = 32; o > 0; o >>= 1) mx = fmaxf(mx, __shfl_xor(mx, o));
      float e = expf(x - mx);
      #pragma unroll
      for (int o = 32; o > 0; o >>= 1) e += __shfl_xor(e, o);
      p.out_logp[(size_t)(m0 + row) * 64 + lane] = x - mx - logf(e);
      if (lane == 0) p.out_value[m0 + row] = lbuf[row * 68 + 64];
    }
    if (item == 0 && wave == 0) {
      float s = p.part1[lane] + p.part2[lane];
      #pragma unroll
      for (int o = 32; o > 0; o >>= 1) s += __shfl_xor(s, o);
      if (lane == 0) p.out_loss[0] = s;
    }
    __syncthreads();
  }
}

// ============================ mega kernel ============================
__global__ __launch_bounds__(256, 2) void mega_kernel(Prm p) {
  extern __shared__ char smem[];
  cg::grid_group grid = cg::this_grid();
  const int nb = gridDim.x;
  ph_prep(p, smem, nb);                                   grid.sync();
  ph_enc(p, smem, nb);                                    grid.sync();
  ph_gates(p, smem, nb);                                  grid.sync();
  ph_gatfeat(p, smem, nb, 4, p.out_h, p.W1T, p.wab1,
             p.pmn, p.pmx, 256, p.part1, p.h1, p.ci1, p.cj1);   grid.sync();
  ph_sort(p, smem, nb, p.cj1, p.skey1, p.sc1, p.pm1, 256); grid.sync();
  ph_scan1(p, nb);                                        grid.sync();
  ph_prefix1(p, nb);                                      grid.sync();
  ph_combine1(p, smem, nb);                               grid.sync();
  ph_gatfeat(p, smem, nb, 1, p.comm1e, p.W2T, p.wab2,
             p.pmn, p.pmx, 4096, p.part2, p.h2b, p.ci2, p.cj2); grid.sync();
  ph_sort(p, smem, nb, p.cj2, p.skey2, p.sc2, p.pm2, 64);  grid.sync();
  ph_scan2(p, smem, nb);                                  grid.sync();
  ph_prefix2(p);                                          grid.sync();
  ph_combine2(p, nb);                                     grid.sync();
  ph_heads(p, smem, nb);
}

// ============================ launch ============================
extern "C" void kernel_launch(void* const* d_in, const int* in_sizes, int n_in,
                              void* d_out, int out_size, void* d_ws, size_t ws_size,
                              hipStream_t stream) {
  Prm P;
  P.obs  = (const float*)d_in[0];
  P.h0   = (const float*)d_in[1];
  P.c0   = (const float*)d_in[2];
  P.Wobs = (const float*)d_in[3];
  P.bobs = (const float*)d_in[4];
  P.Wih  = (const float*)d_in[5];
  P.Whh  = (const float*)d_in[6];
  P.bih  = (const float*)d_in[7];
  P.bhh  = (const float*)d_in[8];
  P.W1   = (const float*)d_in[9];
  P.ai1  = (const float*)d_in[10];
  P.aj1  = (const float*)d_in[11];
  P.b1   = (const float*)d_in[12];
  P.W2   = (const float*)d_in[13];
  P.ai2  = (const float*)d_in[14];
  P.aj2  = (const float*)d_in[15];
  P.b2   = (const float*)d_in[16];
  P.Wv   = (const float*)d_in[17];
  P.bv   = (const float*)d_in[18];
  P.Wa   = (const float*)d_in[19];
  P.ba   = (const float*)d_in[20];

  float* out = (float*)d_out;
  P.out_logp  = out;
  P.out_value = out + 262144;
  P.out_h     = out + 266240;
  P.out_c     = out + 1314816;
  P.out_loss  = out + 2363392;

  char* ws = (char*)d_ws;
  P.part1 = (float*)(ws + 256);
  P.part2 = (float*)(ws + 1280);
  P.pmn   = (float*)(ws + 2304);
  P.pmx   = (float*)(ws + 18688);
  const size_t MB = 1048576;
  const size_t base = 35072;
  P.Wihp     = (ushort*)(ws + base);
  P.Whhp     = (ushort*)(ws + base + 524288);
  P.WobsT    = (ushort*)(ws + base + 1 * MB);
  P.W1T      = (ushort*)(ws + base + 1 * MB + 131072);
  P.W2T      = (ushort*)(ws + base + 1 * MB + 262144);
  P.WaTe     = (ushort*)(ws + base + 1 * MB + 393216);
  P.bias_ext = (float*) (ws + base + 1 * MB + 524288);
  P.bias12   = (float*) (ws + base + 1 * MB + 525312);
  P.wab1     = (ushort*)(ws + base + 1 * MB + 532480);
  P.wab2     = (ushort*)(ws + base + 1 * MB + 540672);
  P.enc_bf   = (ushort*)(ws + base + 2 * MB);
  P.h_bf     = (ushort*)(ws + base + 4 * MB);
  P.comm2_bf = (ushort*)(ws + base + 6 * MB);
  P.h1       = (float*) (ws + base + 8 * MB);
  P.comm1e   = (float*) (ws + base + 12 * MB);
  P.h2b      = (float*) (ws + base + 16 * MB);
  size_t so = base + 20 * MB;
  auto alloc = [&](size_t bytes) { size_t r = so; so += (bytes + 255) & ~255ull; return (char*)ws + r; };
  P.ci1    = (float*)alloc(4 * 4096 * 4);
  P.cj1    = (float*)alloc(4 * 4096 * 4);
  P.skey1  = (unsigned*)alloc(4 * 4096 * 4);
  P.sc1    = (float*)alloc(4 * 4096 * 4);
  P.pm1    = (int*)  alloc(4 * 4096 * 4);
  P.cku1   = (float*)alloc(4 * 64 * 64 * 4);
  P.ckv1   = (float*)alloc(4 * 64 * 64 * 4);
  P.ckus1  = (float*)alloc(4 * 64 * 4);
  P.ckvs1  = (float*)alloc(4 * 64 * 4);
  P.sufU1  = (float*)alloc(4 * 65 * 64 * 4);
  P.prefV1 = (float*)alloc(4 * 65 * 64 * 4);
  P.sufUs1 = (float*)alloc(4 * 65 * 4);
  P.prefVs1= (float*)alloc(4 * 65 * 4);
  P.ci2    = (float*)alloc(4096 * 4);
  P.cj2    = (float*)alloc(4096 * 4);
  P.skey2  = (unsigned*)alloc(4096 * 4);
  P.sc2    = (float*)alloc(4096 * 4);
  P.pm2    = (int*)  alloc(4096 * 4);
  P.cku2   = (float*)alloc(64 * 256 * 4);
  P.ckv2   = (float*)alloc(64 * 256 * 4);
  P.ckus2  = (float*)alloc(64 * 4);
  P.ckvs2  = (float*)alloc(64 * 4);
  P.sufU2  = (float*)alloc(65 * 256 * 4);
  P.prefV2 = (float*)alloc(65 * 256 * 4);
  P.sufUs2 = (float*)alloc(65 * 4);
  P.prefVs2= (float*)alloc(65 * 4);
  P.PUl    = (float*)alloc(4 * 4096 * 64 * 4);
  P.PVl    = (float*)alloc(4 * 4096 * 64 * 4);
  P.dUl    = (float*)alloc(4 * 4096 * 4);
  P.dVl    = (float*)alloc(4 * 4096 * 4);

  const unsigned SMEM = 22528;
  int nblk = 0;
  if (hipOccupancyMaxActiveBlocksPerMultiprocessor(&nblk, mega_kernel, 256,
                                                   (size_t)SMEM) != hipSuccess || nblk < 1)
    nblk = 1;
  int gridBlocks = nblk * 256;
  if (gridBlocks > 512) gridBlocks = 512;
  if (gridBlocks < 256) gridBlocks = 256;

  void* args[] = { (void*)&P };
  hipLaunchCooperativeKernel(mega_kernel, dim3(gridBlocks), dim3(256),
                             args, SMEM, stream);
}

// Round 11
// 252.623 us; speedup vs baseline: 2.9729x; 2.9729x over previous
//
#include <hip/hip_runtime.h>
#include <math.h>

typedef __attribute__((ext_vector_type(8))) short short8;
typedef __attribute__((ext_vector_type(4))) float floatx4;

__device__ __forceinline__ ushort f2b(float f) {
  unsigned u = __float_as_uint(f);
  unsigned r = u + 0x7FFFu + ((u >> 16) & 1u);
  return (ushort)(r >> 16);
}
__device__ __forceinline__ unsigned encf(float f) {
  unsigned u = __float_as_uint(f);
  return (u & 0x80000000u) ? ~u : (u | 0x80000000u);
}

// ====== prep: permuted Wih/Whh conversion, transposes, WaTe, biases, wab ======
// Gate-col permutation: dest col c -> orig row gate*256 + d, where
// gate=(c>>4)&3, d=(c>>6)*16 + (c&15). (64-col block = [i|f|g|o] x 16 units)
__global__ __launch_bounds__(256) void prep_kernel(
    const float* __restrict__ Wih, ushort* __restrict__ Wihp,
    const float* __restrict__ Whh, ushort* __restrict__ Whhp,
    const float* __restrict__ Wobs, ushort* __restrict__ WobsT,
    const float* __restrict__ W1, ushort* __restrict__ W1T,
    const float* __restrict__ W2, ushort* __restrict__ W2T,
    const float* __restrict__ Wa, const float* __restrict__ Wv,
    const float* __restrict__ ba, const float* __restrict__ bv,
    const float* __restrict__ bih, const float* __restrict__ bhh,
    ushort* __restrict__ WaTe, float* __restrict__ bias_ext, float* __restrict__ bias12,
    const float* __restrict__ ai1, const float* __restrict__ aj1,
    const float* __restrict__ ai2, const float* __restrict__ aj2,
    ushort* __restrict__ wab1, ushort* __restrict__ wab2)
{
  __shared__ float tile[32][33];
  const int bid = blockIdx.x;
  const int tid = threadIdx.x;
  if (bid < 512) {
    const int i = bid * 256 + tid;
    const int half = i >> 16;            // 0 = Wih, 1 = Whh
    const int ii = i & 65535;
    const int pr = ii >> 6, k4 = ii & 63;
    const int orow = ((pr >> 4) & 3) * 256 + (pr >> 6) * 16 + (pr & 15);
    const float* s = half ? Whh : Wih;
    ushort* d = half ? Whhp : Wihp;
    const float4 v = *(const float4*)(s + (size_t)orow * 256 + k4 * 4);
    ushort4 o; o.x = f2b(v.x); o.y = f2b(v.y); o.z = f2b(v.z); o.w = f2b(v.w);
    *(ushort4*)(d + (size_t)pr * 256 + k4 * 4) = o;
  } else if (bid < 704) {
    const int t = bid - 512;
    const int mat = t >> 6, sub = t & 63;
    const float* in = mat == 0 ? Wobs : (mat == 1 ? W1 : W2);
    ushort* outp = mat == 0 ? WobsT : (mat == 1 ? W1T : W2T);
    const int c0 = (sub & 7) * 32, r0 = (sub >> 3) * 32;
    const int tx = tid & 31, ty = tid >> 5;
    #pragma unroll
    for (int p = 0; p < 32; p += 8)
      tile[ty + p][tx] = in[(size_t)(r0 + ty + p) * 256 + c0 + tx];
    __syncthreads();
    #pragma unroll
    for (int p = 0; p < 32; p += 8)
      outp[(size_t)(c0 + ty + p) * 256 + r0 + tx] = f2b(tile[tx][ty + p]);
  } else if (bid < 965) {
    const int idx = (bid - 704) * 256 + tid;
    if (idx < 65536) {
      const int n = idx >> 9, k = idx & 511;
      const float v = n < 64 ? Wa[(size_t)k * 64 + n] : (n == 64 ? Wv[k] : 0.0f);
      WaTe[idx] = f2b(v);
    } else if (idx < 65536 + 128) {
      const int n = idx - 65536;
      bias_ext[n] = n < 64 ? ba[n] : (n == 64 ? bv[0] : 0.0f);
    } else if (idx < 65536 + 128 + 1024) {
      const int pc = idx - 65536 - 128;
      const int orow = ((pc >> 4) & 3) * 256 + (pc >> 6) * 16 + (pc & 15);
      bias12[pc] = bih[orow] + bhh[orow];
    }
  } else if (bid < 981) {
    // wab1[16][256]: c<4 -> W1^T ai1 head c ; c in [4,8) -> W1^T aj1 ; else 0
    const int c = bid - 965;
    const int k = tid;
    float val = 0.0f;
    if (c < 8) {
      const int h = c & 3;
      const float* av = (c < 4) ? ai1 : aj1;
      for (int g = 0; g < 64; ++g)
        val += W1[(size_t)k * 256 + h * 64 + g] * av[h * 64 + g];
    }
    wab1[c * 256 + k] = f2b(val);
  } else {
    // wab2[16][256]: c==0 -> W2^T ai2 ; c==1 -> W2^T aj2 ; else 0
    const int c = bid - 981;
    const int k = tid;
    float val = 0.0f;
    if (c < 2) {
      const float* av = (c == 0) ? ai2 : aj2;
      for (int g = 0; g < 256; ++g)
        val += W2[(size_t)k * 256 + g] * av[g];
    }
    wab2[c * 256 + k] = f2b(val);
  }
}

// ===== enc GEMM: enc_bf = bf16(obs @ WobsT^T + bobs); A fp32 converted in staging =====
__global__ __launch_bounds__(256) void enc_gemm(
    const float* __restrict__ obs, const ushort* __restrict__ WobsT,
    const float* __restrict__ bobs, ushort* __restrict__ enc_bf)
{
  constexpr int LDT = 40;
  __shared__ __align__(16) ushort As[64 * LDT];
  __shared__ __align__(16) ushort Bs[64 * LDT];
  const int tid = threadIdx.x;
  const int wave = tid >> 6, lane = tid & 63;
  const int wr = wave >> 1, wc = wave & 1;
  const int m0 = blockIdx.y * 64, n0 = blockIdx.x * 64;
  floatx4 acc[2][2] = {};
  const int r = tid >> 2, kq = tid & 3;
  const int lm = lane & 15, lq = lane >> 4;
  for (int k0 = 0; k0 < 256; k0 += 32) {
    {
      const float* s = &obs[(size_t)(m0 + r) * 256 + k0 + kq * 8];
      const float4 a = *(const float4*)s;
      const float4 b = *(const float4*)(s + 4);
      ushort4 o1, o2;
      o1.x = f2b(a.x); o1.y = f2b(a.y); o1.z = f2b(a.z); o1.w = f2b(a.w);
      o2.x = f2b(b.x); o2.y = f2b(b.y); o2.z = f2b(b.z); o2.w = f2b(b.w);
      *(ushort4*)&As[r * LDT + kq * 8] = o1;
      *(ushort4*)&As[r * LDT + kq * 8 + 4] = o2;
      *(float4*)&Bs[r * LDT + kq * 8] =
          *(const float4*)&WobsT[(size_t)(n0 + r) * 256 + k0 + kq * 8];
    }
    __syncthreads();
    short8 af[2], bfr[2];
    #pragma unroll
    for (int i = 0; i < 2; ++i)
      af[i] = *(const short8*)&As[(wr * 32 + i * 16 + lm) * LDT + lq * 8];
    #pragma unroll
    for (int j = 0; j < 2; ++j)
      bfr[j] = *(const short8*)&Bs[(wc * 32 + j * 16 + lm) * LDT + lq * 8];
    #pragma unroll
    for (int i = 0; i < 2; ++i)
      #pragma unroll
      for (int j = 0; j < 2; ++j)
        acc[i][j] = __builtin_amdgcn_mfma_f32_16x16x32_bf16(af[i], bfr[j], acc[i][j], 0, 0, 0);
    __syncthreads();
  }
  #pragma unroll
  for (int i = 0; i < 2; ++i)
    #pragma unroll
    for (int j = 0; j < 2; ++j) {
      const int col = n0 + wc * 32 + j * 16 + lm;
      const float badd = bobs[col];
      #pragma unroll
      for (int t = 0; t < 4; ++t) {
        const int row = m0 + wr * 32 + i * 16 + lq * 4 + t;
        enc_bf[(size_t)row * 256 + col] = f2b(acc[i][j][t] + badd);
      }
    }
}

// ===== fused gates GEMM (gate-permuted cols) + register LSTM + minmax =====
// grid (8, 32). A: enc_bf (k<256) then h0 fp32 (converted in staging).
__global__ __launch_bounds__(256) void gates_lstm_kernel(
    const ushort* __restrict__ enc_bf, const ushort* __restrict__ Wihp,
    const float* __restrict__ h0, const ushort* __restrict__ Whhp,
    const float* __restrict__ bias12p, const float* __restrict__ c0,
    float* __restrict__ h_out, float* __restrict__ c_out, ushort* __restrict__ h_bf,
    float* __restrict__ pmn, float* __restrict__ pmx)
{
  constexpr int LDT = 40;
  __shared__ __align__(16) ushort As[128 * LDT];
  __shared__ __align__(16) ushort Bs[128 * LDT];
  __shared__ float smn[4], smx[4];
  const int tid = threadIdx.x;
  const int wave = tid >> 6, lane = tid & 63;
  const int wr = wave >> 1, wc = wave & 1;
  const int m0 = blockIdx.y * 128, n0 = blockIdx.x * 128;
  floatx4 acc[4][4] = {};
  const int r = tid >> 2, kq = tid & 3;
  const int lm = lane & 15, lq = lane >> 4;
  for (int k0 = 0; k0 < 512; k0 += 32) {
    const ushort* B = (k0 < 256) ? Wihp : Whhp;
    const int kk = (k0 < 256) ? k0 : k0 - 256;
    if (k0 < 256) {
      #pragma unroll
      for (int p = 0; p < 2; ++p) {
        const int rr = r + p * 64;
        *(float4*)&As[rr * LDT + kq * 8] =
            *(const float4*)&enc_bf[(size_t)(m0 + rr) * 256 + kk + kq * 8];
      }
    } else {
      #pragma unroll
      for (int p = 0; p < 2; ++p) {
        const int rr = r + p * 64;
        const float* s = &h0[(size_t)(m0 + rr) * 256 + kk + kq * 8];
        const float4 a = *(const float4*)s;
        const float4 b = *(const float4*)(s + 4);
        ushort4 o1, o2;
        o1.x = f2b(a.x); o1.y = f2b(a.y); o1.z = f2b(a.z); o1.w = f2b(a.w);
        o2.x = f2b(b.x); o2.y = f2b(b.y); o2.z = f2b(b.z); o2.w = f2b(b.w);
        *(ushort4*)&As[rr * LDT + kq * 8] = o1;
        *(ushort4*)&As[rr * LDT + kq * 8 + 4] = o2;
      }
    }
    #pragma unroll
    for (int p = 0; p < 2; ++p) {
      const int rr = r + p * 64;
      *(float4*)&Bs[rr * LDT + kq * 8] =
          *(const float4*)&B[(size_t)(n0 + rr) * 256 + kk + kq * 8];
    }
    __syncthreads();
    short8 af[4], bfr[4];
    #pragma unroll
    for (int i = 0; i < 4; ++i)
      af[i] = *(const short8*)&As[(wr * 64 + i * 16 + lm) * LDT + lq * 8];
    #pragma unroll
    for (int j = 0; j < 4; ++j)
      bfr[j] = *(const short8*)&Bs[(wc * 64 + j * 16 + lm) * LDT + lq * 8];
    #pragma unroll
    for (int i = 0; i < 4; ++i)
      #pragma unroll
      for (int j = 0; j < 4; ++j)
        acc[i][j] = __builtin_amdgcn_mfma_f32_16x16x32_bf16(af[i], bfr[j], acc[i][j], 0, 0, 0);
    __syncthreads();
  }
  // register LSTM epilogue: lane owns unit d, j-tile = gate
  const int d = (blockIdx.x * 2 + wc) * 16 + lm;
  float b4[4];
  #pragma unroll
  for (int j = 0; j < 4; ++j) b4[j] = bias12p[n0 + wc * 64 + j * 16 + lm];
  float mnl = 3.0e38f, mxl = -3.0e38f;
  #pragma unroll
  for (int i = 0; i < 4; ++i) {
    #pragma unroll
    for (int t = 0; t < 4; ++t) {
      const int row = m0 + wr * 64 + i * 16 + lq * 4 + t;
      const size_t off = (size_t)row * 256 + d;
      const float gi = acc[i][0][t] + b4[0];
      const float gf = acc[i][1][t] + b4[1];
      const float gg = acc[i][2][t] + b4[2];
      const float go = acc[i][3][t] + b4[3];
      const float cc = c0[off];
      const float si = 1.0f / (1.0f + expf(-gi));
      const float sf = 1.0f / (1.0f + expf(-gf));
      const float so = 1.0f / (1.0f + expf(-go));
      const float c2 = sf * cc + si * tanhf(gg);
      const float h2 = so * tanhf(c2);
      h_out[off] = h2;
      c_out[off] = c2;
      h_bf[off] = f2b(h2);
      mnl = fminf(mnl, h2); mxl = fmaxf(mxl, h2);
    }
  }
  #pragma unroll
  for (int o = 32; o > 0; o >>= 1) {
    mnl = fminf(mnl, __shfl_xor(mnl, o));
    mxl = fmaxf(mxl, __shfl_xor(mxl, o));
  }
  if (lane == 0) { smn[wave] = mnl; smx[wave] = mxl; }
  __syncthreads();
  if (tid == 0) {
    const int bid = blockIdx.y * 8 + blockIdx.x;
    pmn[bid] = fminf(fminf(smn[0], smn[1]), fminf(smn[2], smn[3]));
    pmx[bid] = fmaxf(fmaxf(smx[0], smx[1]), fmaxf(smx[2], smx[3]));
  }
}

// === fake-quant (fused global min/max from partials) -> bf16 + loss partial ===
__global__ __launch_bounds__(256) void quant_kernel(
    const float4* __restrict__ x, ushort* __restrict__ q, int n4,
    const float* __restrict__ pmn, const float* __restrict__ pmx, int np,
    float* __restrict__ part)
{
  __shared__ float smn[4], smx[4], sl[4], bmn, bmx;
  float mn = 3.0e38f, mx = -3.0e38f;
  for (int i = threadIdx.x; i < np; i += 256) {
    mn = fminf(mn, pmn[i]); mx = fmaxf(mx, pmx[i]);
  }
  #pragma unroll
  for (int o = 32; o > 0; o >>= 1) {
    mn = fminf(mn, __shfl_xor(mn, o));
    mx = fmaxf(mx, __shfl_xor(mx, o));
  }
  if ((threadIdx.x & 63) == 0) { smn[threadIdx.x >> 6] = mn; smx[threadIdx.x >> 6] = mx; }
  __syncthreads();
  if (threadIdx.x == 0) {
    bmn = fminf(fminf(smn[0], smn[1]), fminf(smn[2], smn[3]));
    bmx = fmaxf(fmaxf(smx[0], smx[1]), fmaxf(smx[2], smx[3]));
  }
  __syncthreads();
  mn = bmn; mx = bmx;
  if (mn == mx) { mn -= 0.01f; mx += 0.01f; }
  const float scale = (mx - mn) / 255.0f;
  const float zp = rintf(-mn / scale);
  float lsum = 0.0f;
  for (int idx = blockIdx.x * 256 + threadIdx.x; idx < n4; idx += gridDim.x * 256) {
    const float4 t = x[idx];
    float d0, d1, d2, d3;
    { float qq = fminf(fmaxf(rintf(t.x / scale + zp), 0.0f), 255.0f);
      d0 = (qq - zp) * scale; lsum += log2f(510.0f * fabsf(d0) + 1.0f); }
    { float qq = fminf(fmaxf(rintf(t.y / scale + zp), 0.0f), 255.0f);
      d1 = (qq - zp) * scale; lsum += log2f(510.0f * fabsf(d1) + 1.0f); }
    { float qq = fminf(fmaxf(rintf(t.z / scale + zp), 0.0f), 255.0f);
      d2 = (qq - zp) * scale; lsum += log2f(510.0f * fabsf(d2) + 1.0f); }
    { float qq = fminf(fmaxf(rintf(t.w / scale + zp), 0.0f), 255.0f);
      d3 = (qq - zp) * scale; lsum += log2f(510.0f * fabsf(d3) + 1.0f); }
    ushort4 o; o.x = f2b(d0); o.y = f2b(d1); o.z = f2b(d2); o.w = f2b(d3);
    *(ushort4*)(q + (size_t)idx * 4) = o;
  }
  #pragma unroll
  for (int o = 32; o > 0; o >>= 1) lsum += __shfl_xor(lsum, o);
  if ((threadIdx.x & 63) == 0) sl[threadIdx.x >> 6] = lsum;
  __syncthreads();
  if (threadIdx.x == 0) part[blockIdx.x] = sl[0] + sl[1] + sl[2] + sl[3];
}

// ==== GAT features: blocks 0..255 = h GEMM (fp32 out), 256..319 = ci/cj MFMA ====
template<int HN>
__global__ __launch_bounds__(256) void gat_feat_kernel(
    const ushort* __restrict__ Aq, const ushort* __restrict__ WT,
    const ushort* __restrict__ wab,
    float* __restrict__ hout, float* __restrict__ ci, float* __restrict__ cj)
{
  constexpr int LDT = 40;
  __shared__ __align__(16) ushort As[64 * LDT];
  __shared__ __align__(16) ushort Bs[64 * LDT];
  const int bid = blockIdx.x;
  const int tid = threadIdx.x;
  const int wave = tid >> 6, lane = tid & 63;
  const int lm = lane & 15, lq = lane >> 4;
  const int r = tid >> 2, kq = tid & 3;
  if (bid < 256) {
    const int bx = bid & 3, by = bid >> 2;
    const int m0 = by * 64, n0 = bx * 64;
    const int wr = wave >> 1, wc = wave & 1;
    floatx4 acc[2][2] = {};
    for (int k0 = 0; k0 < 256; k0 += 32) {
      *(float4*)&As[r * LDT + kq * 8] =
          *(const float4*)&Aq[(size_t)(m0 + r) * 256 + k0 + kq * 8];
      *(float4*)&Bs[r * LDT + kq * 8] =
          *(const float4*)&WT[(size_t)(n0 + r) * 256 + k0 + kq * 8];
      __syncthreads();
      short8 af[2], bfr[2];
      #pragma unroll
      for (int i = 0; i < 2; ++i)
        af[i] = *(const short8*)&As[(wr * 32 + i * 16 + lm) * LDT + lq * 8];
      #pragma unroll
      for (int j = 0; j < 2; ++j)
        bfr[j] = *(const short8*)&Bs[(wc * 32 + j * 16 + lm) * LDT + lq * 8];
      #pragma unroll
      for (int i = 0; i < 2; ++i)
        #pragma unroll
        for (int j = 0; j < 2; ++j)
          acc[i][j] = __builtin_amdgcn_mfma_f32_16x16x32_bf16(af[i], bfr[j], acc[i][j], 0, 0, 0);
      __syncthreads();
    }
    #pragma unroll
    for (int i = 0; i < 2; ++i)
      #pragma unroll
      for (int j = 0; j < 2; ++j) {
        const int col = n0 + wc * 32 + j * 16 + lm;
        #pragma unroll
        for (int t = 0; t < 4; ++t) {
          const int row = m0 + wr * 32 + i * 16 + lq * 4 + t;
          hout[(size_t)row * 256 + col] = acc[i][j][t];
        }
      }
  } else {
    // ci/cj: [64 rows] x [16 cols] MFMA against wab
    const int m0 = (bid - 256) * 64;
    floatx4 acc = {0.f, 0.f, 0.f, 0.f};
    for (int k0 = 0; k0 < 256; k0 += 32) {
      *(float4*)&As[r * LDT + kq * 8] =
          *(const float4*)&Aq[(size_t)(m0 + r) * 256 + k0 + kq * 8];
      if (r < 16)
        *(float4*)&Bs[r * LDT + kq * 8] =
            *(const float4*)&wab[(size_t)r * 256 + k0 + kq * 8];
      __syncthreads();
      const short8 af = *(const short8*)&As[(wave * 16 + lm) * LDT + lq * 8];
      const short8 bf = *(const short8*)&Bs[lm * LDT + lq * 8];
      acc = __builtin_amdgcn_mfma_f32_16x16x32_bf16(af, bf, acc, 0, 0, 0);
      __syncthreads();
    }
    #pragma unroll
    for (int t = 0; t < 4; ++t) {
      const int row = m0 + wave * 16 + lq * 4 + t;
      if (lm < HN) ci[lm * 4096 + row] = acc[t];
      else if (lm < 2 * HN) cj[(lm - HN) * 4096 + row] = acc[t];
    }
  }
}

// ====== rank sort, u32 keys (top-20 value bits | 12-bit idx) ======
__global__ __launch_bounds__(1024) void rank_sort_kernel(
    const float* __restrict__ c, unsigned* __restrict__ skey,
    float* __restrict__ sc, int* __restrict__ pm)
{
  __shared__ unsigned lk[4096];
  __shared__ int scnt[16][64];
  const int head = blockIdx.x >> 6;
  const int seg = blockIdx.x & 63;
  const float* ch = c + head * 4096;
  for (int idx = threadIdx.x; idx < 4096; idx += 1024)
    lk[idx] = (encf(ch[idx]) & 0xFFFFF000u) | (unsigned)idx;
  __syncthreads();
  const int jl = threadIdx.x & 63;
  const int kg = threadIdx.x >> 6;
  const unsigned my = lk[seg * 64 + jl];
  int cnt = 0;
  const int k0 = kg * 256;
  #pragma unroll 8
  for (int k = k0; k < k0 + 256; ++k)
    cnt += lk[k] < my ? 1 : 0;
  scnt[kg][jl] = cnt;
  __syncthreads();
  if (threadIdx.x < 64) {
    int rank = 0;
    #pragma unroll
    for (int g = 0; g < 16; ++g) rank += scnt[g][threadIdx.x];
    const unsigned kk = lk[seg * 64 + threadIdx.x];
    const int jj = (int)(kk & 0xFFFu);
    skey[head * 4096 + rank] = kk;
    sc[head * 4096 + rank] = ch[jj];
    pm[head * 4096 + rank] = jj;
  }
}

// ======= local scan (GAT1): 2 waves/block, wave0=PV asc, wave1=PU desc =======
__global__ __launch_bounds__(128) void local_scan1(
    const float* __restrict__ h1, const float* __restrict__ sc, const int* __restrict__ pm,
    float* __restrict__ PUl, float* __restrict__ PVl,
    float* __restrict__ dUl, float* __restrict__ dVl,
    float* __restrict__ cku, float* __restrict__ ckv,
    float* __restrict__ ckus, float* __restrict__ ckvs)
{
  const int head = blockIdx.x >> 6;
  const int chunk = blockIdx.x & 63;
  const int wave = threadIdx.x >> 6;
  const int lane = threadIdx.x & 63;
  const float cmax = sc[head * 4096 + 4095];
  const int base = head * 4096 + chunk * 64;
  const float cv = sc[base + lane];
  const float u = expf(cv - cmax);
  const float v = expf(0.2f * (cv - cmax));
  const int myj = pm[base + lane];
  const float* hrow = h1 + head * 64 + lane;
  if (wave == 0) {
    float iu = u, iv = v;
    #pragma unroll
    for (int o = 1; o < 64; o <<= 1) {
      const float tu = __shfl_up(iu, o), tv = __shfl_up(iv, o);
      if (lane >= o) { iu += tu; iv += tv; }
    }
    const float totU = __shfl(iu, 63), totV = __shfl(iv, 63);
    dVl[base + lane] = iv - v;
    dUl[base + lane] = totU - (iu - u);
    if (lane == 0) { ckus[head * 64 + chunk] = totU; ckvs[head * 64 + chunk] = totV; }
    float accV = 0.f;
    #pragma unroll 16
    for (int k = 0; k < 64; ++k) {
      const float vk = __shfl(v, k);
      const int j = __shfl(myj, k);
      PVl[(size_t)(base + k) * 64 + lane] = accV;
      accV += vk * hrow[(size_t)j * 256];
    }
    ckv[(head * 64 + chunk) * 64 + lane] = accV;
  } else {
    float accU = 0.f;
    #pragma unroll 16
    for (int k = 63; k >= 0; --k) {
      const float uk = __shfl(u, k);
      const int j = __shfl(myj, k);
      accU += uk * hrow[(size_t)j * 256];
      PUl[(size_t)(base + k) * 64 + lane] = accU;
    }
    cku[(head * 64 + chunk) * 64 + lane] = accU;
  }
}

// === local scan (GAT2, g=256): grid (colgrp=2, chunk=64); waves 0-1 PV, 2-3 PU ===
__global__ __launch_bounds__(256) void local_scan2(
    const float* __restrict__ h2, const float* __restrict__ sc, const int* __restrict__ pm,
    float* __restrict__ PUl, float* __restrict__ PVl,
    float* __restrict__ dUl, float* __restrict__ dVl,
    float* __restrict__ cku, float* __restrict__ ckv,
    float* __restrict__ ckus, float* __restrict__ ckvs)
{
  __shared__ float su[64], sv[64];
  __shared__ int sj[64];
  const int chunk = blockIdx.y;
  const int colgrp = blockIdx.x;
  const int tid = threadIdx.x;
  const int wave = tid >> 6, lane = tid & 63;
  const float cmax = sc[4095];
  const int base = chunk * 64;
  if (tid < 64) {
    const float cv = sc[base + tid];
    const float u = expf(cv - cmax);
    const float v = expf(0.2f * (cv - cmax));
    su[tid] = u; sv[tid] = v; sj[tid] = pm[base + tid];
    if (colgrp == 0) {
      float iu = u, iv = v;
      #pragma unroll
      for (int o = 1; o < 64; o <<= 1) {
        const float tu = __shfl_up(iu, o), tv = __shfl_up(iv, o);
        if (lane >= o) { iu += tu; iv += tv; }
      }
      const float totU = __shfl(iu, 63), totV = __shfl(iv, 63);
      dVl[base + lane] = iv - v;
      dUl[base + lane] = totU - (iu - u);
      if (lane == 0) { ckus[chunk] = totU; ckvs[chunk] = totV; }
    }
  }
  __syncthreads();
  const int col = colgrp * 128 + (wave & 1) * 64 + lane;
  if (wave < 2) {
    float accV = 0.f;
    #pragma unroll 16
    for (int k = 0; k < 64; ++k) {
      PVl[(size_t)(base + k) * 256 + col] = accV;
      accV += sv[k] * h2[(size_t)sj[k] * 256 + col];
    }
    ckv[chunk * 256 + col] = accV;
  } else {
    float accU = 0.f;
    #pragma unroll 16
    for (int k = 63; k >= 0; --k) {
      accU += su[k] * h2[(size_t)sj[k] * 256 + col];
      PUl[(size_t)(base + k) * 256 + col] = accU;
    }
    cku[chunk * 256 + col] = accU;
  }
}

// ======= chunk prefix/suffix: lane=col (coalesced), serial chunk loop =======
__global__ __launch_bounds__(64) void prefix1_kernel(
    const float* __restrict__ cku, const float* __restrict__ ckv,
    const float* __restrict__ ckus, const float* __restrict__ ckvs,
    float* __restrict__ sufU, float* __restrict__ prefV,
    float* __restrict__ sufUs, float* __restrict__ prefVs)
{
  const int head = blockIdx.x, lane = threadIdx.x;
  float acc = 0.f;
  for (int c = 0; c < 64; ++c) {
    prefV[(head * 65 + c) * 64 + lane] = acc;
    acc += ckv[(head * 64 + c) * 64 + lane];
  }
  prefV[(head * 65 + 64) * 64 + lane] = acc;
  acc = 0.f;
  sufU[(head * 65 + 64) * 64 + lane] = 0.f;
  for (int c = 63; c >= 0; --c) {
    acc += cku[(head * 64 + c) * 64 + lane];
    sufU[(head * 65 + c) * 64 + lane] = acc;
  }
  {
    const float vs = ckvs[head * 64 + lane];
    const float us = ckus[head * 64 + lane];
    float iv = vs, iu = us;
    #pragma unroll
    for (int o = 1; o < 64; o <<= 1) {
      const float tv = __shfl_up(iv, o), tu = __shfl_up(iu, o);
      if (lane >= o) { iv += tv; iu += tu; }
    }
    prefVs[head * 65 + lane] = iv - vs;
    const float totU = __shfl(iu, 63);
    sufUs[head * 65 + lane] = totU - iu + us;
    if (lane == 63) {
      prefVs[head * 65 + 64] = iv;
      sufUs[head * 65 + 64] = 0.f;
    }
  }
}

__global__ __launch_bounds__(256) void prefix2_kernel(
    const float* __restrict__ cku, const float* __restrict__ ckv,
    const float* __restrict__ ckus, const float* __restrict__ ckvs,
    float* __restrict__ sufU, float* __restrict__ prefV,
    float* __restrict__ sufUs, float* __restrict__ prefVs)
{
  const int col = threadIdx.x;
  const int lane = col & 63;
  float acc = 0.f;
  for (int c = 0; c < 64; ++c) {
    prefV[c * 256 + col] = acc;
    acc += ckv[c * 256 + col];
  }
  prefV[64 * 256 + col] = acc;
  acc = 0.f;
  sufU[64 * 256 + col] = 0.f;
  for (int c = 63; c >= 0; --c) {
    acc += cku[c * 256 + col];
    sufU[c * 256 + col] = acc;
  }
  if (col < 64) {
    const float vs = ckvs[lane];
    const float us = ckus[lane];
    float iv = vs, iu = us;
    #pragma unroll
    for (int o = 1; o < 64; o <<= 1) {
      const float tv = __shfl_up(iv, o), tu = __shfl_up(iu, o);
      if (lane >= o) { iv += tv; iu += tu; }
    }
    prefVs[lane] = iv - vs;
    const float totU = __shfl(iu, 63);
    sufUs[lane] = totU - iu + us;
    if (lane == 63) { prefVs[64] = iv; sufUs[64] = 0.f; }
  }
}

// ====== GAT1 combine: lookup via u32-key binary search + minmax ======
__global__ __launch_bounds__(256) void combine1_kernel(
    const float* __restrict__ ci, const unsigned* __restrict__ skey,
    const float* __restrict__ sc,
    const float* __restrict__ sufU, const float* __restrict__ prefV,
    const float* __restrict__ sufUs, const float* __restrict__ prefVs,
    const float* __restrict__ PUl, const float* __restrict__ PVl,
    const float* __restrict__ dUl, const float* __restrict__ dVl,
    const float* __restrict__ b1, float* __restrict__ out,
    float* __restrict__ pmn, float* __restrict__ pmx)
{
  const int i = blockIdx.x;
  const int head = threadIdx.x >> 6;
  const int lane = threadIdx.x & 63;
  const unsigned* skh = skey + head * 4096;
  const float civ = ci[head * 4096 + i];
  const float cmax = sc[head * 4096 + 4095];
  const float sarg = civ + cmax;
  const float m = sarg > 0.f ? sarg : 0.2f * sarg;
  const float Af = expf(sarg - m);
  const float Bf = expf(0.2f * sarg - m);
  const unsigned tkey = (encf(-civ) & 0xFFFFF000u) | 0xFFFu;
  int lo = 0, hi = 4096;
  while (lo < hi) {
    const int mid = (lo + hi) >> 1;
    if (skh[mid] > tkey) hi = mid; else lo = mid + 1;
  }
  const int s = lo;
  float accP, accN, dP, dN;
  if (s == 4096) {
    accP = 0.f; dP = 0.f;
    accN = prefV[(head * 65 + 64) * 64 + lane];
    dN = prefVs[head * 65 + 64];
  } else {
    const int cs = s >> 6;
    accP = sufU[(head * 65 + cs + 1) * 64 + lane] + PUl[(size_t)(head * 4096 + s) * 64 + lane];
    accN = prefV[(head * 65 + cs) * 64 + lane] + PVl[(size_t)(head * 4096 + s) * 64 + lane];
    dP = sufUs[head * 65 + cs + 1] + dUl[head * 4096 + s];
    dN = prefVs[head * 65 + cs] + dVl[head * 4096 + s];
  }
  const float num = Af * accP + Bf * accN;
  const float den = Af * dP + Bf * dN;
  const float o = num / den + b1[head * 64 + lane];
  const float oe = o > 0.f ? o : expm1f(o);
  out[(size_t)i * 256 + head * 64 + lane] = oe;
  float mn = oe, mx = oe;
  #pragma unroll
  for (int of = 32; of > 0; of >>= 1) {
    mn = fminf(mn, __shfl_xor(mn, of));
    mx = fmaxf(mx, __shfl_xor(mx, of));
  }
  __shared__ float smn[4], smx[4];
  if (lane == 0) { smn[head] = mn; smx[head] = mx; }
  __syncthreads();
  if (threadIdx.x == 0) {
    pmn[i] = fminf(fminf(smn[0], smn[1]), fminf(smn[2], smn[3]));
    pmx[i] = fmaxf(fmaxf(smx[0], smx[1]), fmaxf(smx[2], smx[3]));
  }
}

// ========= GAT2 combine: lookup via u32-key search, writes bf16 =========
__global__ __launch_bounds__(256) void combine2_kernel(
    const float* __restrict__ ci, const unsigned* __restrict__ skey,
    const float* __restrict__ sc,
    const float* __restrict__ sufU, const float* __restrict__ prefV,
    const float* __restrict__ sufUs, const float* __restrict__ prefVs,
    const float* __restrict__ PUl, const float* __restrict__ PVl,
    const float* __restrict__ dUl, const float* __restrict__ dVl,
    const float* __restrict__ b2, ushort* __restrict__ outb)
{
  const int i = blockIdx.x;
  const int col = threadIdx.x;
  const float civ = ci[i];
  const float cmax = sc[4095];
  const float sarg = civ + cmax;
  const float m = sarg > 0.f ? sarg : 0.2f * sarg;
  const float Af = expf(sarg - m);
  const float Bf = expf(0.2f * sarg - m);
  const unsigned tkey = (encf(-civ) & 0xFFFFF000u) | 0xFFFu;
  int lo = 0, hi = 4096;
  while (lo < hi) {
    const int mid = (lo + hi) >> 1;
    if (skey[mid] > tkey) hi = mid; else lo = mid + 1;
  }
  const int s = lo;
  float accP, accN, dP, dN;
  if (s == 4096) {
    accP = 0.f; dP = 0.f;
    accN = prefV[64 * 256 + col];
    dN = prefVs[64];
  } else {
    const int cs = s >> 6;
    accP = sufU[(cs + 1) * 256 + col] + PUl[(size_t)s * 256 + col];
    accN = prefV[cs * 256 + col] + PVl[(size_t)s * 256 + col];
    dP = sufUs[cs + 1] + dUl[s];
    dN = prefVs[cs] + dVl[s];
  }
  const float num = Af * accP + Bf * accN;
  const float den = Af * dP + Bf * dN;
  outb[(size_t)i * 256 + col] = f2b(num / den + b2[col]);
}

// ==== heads: [h|comm2]@WaTe^T + bias, fused log-softmax + value + loss ====
__global__ __launch_bounds__(256) void heads_kernel(
    const ushort* __restrict__ h_bf, const ushort* __restrict__ comm2_bf,
    const ushort* __restrict__ WaTe, const float* __restrict__ bias_ext,
    float* __restrict__ out_logp, float* __restrict__ out_value,
    const float* __restrict__ p1, const float* __restrict__ p2,
    float* __restrict__ out_loss)
{
  constexpr int LDT = 40;
  __shared__ __align__(16) ushort As[64 * LDT];
  __shared__ __align__(16) ushort Bs[128 * LDT];
  __shared__ float lbuf[64][68];
  const int tid = threadIdx.x;
  const int wave = tid >> 6, lane = tid & 63;
  const int wr = wave >> 1, wc = wave & 1;
  const int m0 = blockIdx.x * 64;
  const int lm = lane & 15, lq = lane >> 4;
  floatx4 acc[2][4] = {};
  const int r = tid >> 2, kq = tid & 3;
  for (int k0 = 0; k0 < 512; k0 += 32) {
    const ushort* Asrc = (k0 < 256) ? h_bf : comm2_bf;
    const int kk = (k0 < 256) ? k0 : k0 - 256;
    *(float4*)&As[r * LDT + kq * 8] =
        *(const float4*)&Asrc[(size_t)(m0 + r) * 256 + kk + kq * 8];
    #pragma unroll
    for (int p = 0; p < 2; ++p) {
      const int rr = r + p * 64;
      *(float4*)&Bs[rr * LDT + kq * 8] =
          *(const float4*)&WaTe[(size_t)rr * 512 + k0 + kq * 8];
    }
    __syncthreads();
    short8 af[2], bfr[4];
    #pragma unroll
    for (int i = 0; i < 2; ++i)
      af[i] = *(const short8*)&As[(wr * 32 + i * 16 + lm) * LDT + lq * 8];
    #pragma unroll
    for (int j = 0; j < 4; ++j)
      bfr[j] = *(const short8*)&Bs[(wc * 64 + j * 16 + lm) * LDT + lq * 8];
    #pragma unroll
    for (int i = 0; i < 2; ++i)
      #pragma unroll
      for (int j = 0; j < 4; ++j)
        acc[i][j] = __builtin_amdgcn_mfma_f32_16x16x32_bf16(af[i], bfr[j], acc[i][j], 0, 0, 0);
    __syncthreads();
  }
  #pragma unroll
  for (int i = 0; i < 2; ++i)
    #pragma unroll
    for (int j = 0; j < 4; ++j) {
      const int col = wc * 64 + j * 16 + lm;
      if (col < 65) {
        const float badd = bias_ext[col];
        #pragma unroll
        for (int t = 0; t < 4; ++t)
          lbuf[wr * 32 + i * 16 + lq * 4 + t][col] = acc[i][j][t] + badd;
      }
    }
  __syncthreads();
  for (int rr2 = 0; rr2 < 16; ++rr2) {
    const int row = wave * 16 + rr2;
    const float x = lbuf[row][lane];
    float mx = x;
    #pragma unroll
    for (int o = 32; o > 0; o >>= 1) mx = fmaxf(mx, __shfl_xor(mx, o));
    float e = expf(x - mx);
    #pragma unroll
    for (int o = 32; o > 0; o >>= 1) e += __shfl_xor(e, o);
    out_logp[(size_t)(m0 + row) * 64 + lane] = x - mx - logf(e);
    if (lane == 0) out_value[m0 + row] = lbuf[row][64];
  }
  if (blockIdx.x == 0 && wave == 0) {
    float s = 0.f;
    #pragma unroll
    for (int k = 0; k < 4; ++k) s += p1[lane + k * 64] + p2[lane + k * 64];
    #pragma unroll
    for (int o = 32; o > 0; o >>= 1) s += __shfl_xor(s, o);
    if (lane == 0) out_loss[0] = s;
  }
}

// ============================ launch ============================
extern "C" void kernel_launch(void* const* d_in, const int* in_sizes, int n_in,
                              void* d_out, int out_size, void* d_ws, size_t ws_size,
                              hipStream_t stream) {
  const float* obs  = (const float*)d_in[0];
  const float* h0   = (const float*)d_in[1];
  const float* c0   = (const float*)d_in[2];
  const float* Wobs = (const float*)d_in[3];
  const float* bobs = (const float*)d_in[4];
  const float* Wih  = (const float*)d_in[5];
  const float* Whh  = (const float*)d_in[6];
  const float* bih  = (const float*)d_in[7];
  const float* bhh  = (const float*)d_in[8];
  const float* W1   = (const float*)d_in[9];
  const float* ai1  = (const float*)d_in[10];
  const float* aj1  = (const float*)d_in[11];
  const float* b1   = (const float*)d_in[12];
  const float* W2   = (const float*)d_in[13];
  const float* ai2  = (const float*)d_in[14];
  const float* aj2  = (const float*)d_in[15];
  const float* b2   = (const float*)d_in[16];
  const float* Wv   = (const float*)d_in[17];
  const float* bv   = (const float*)d_in[18];
  const float* Wa   = (const float*)d_in[19];
  const float* ba   = (const float*)d_in[20];

  float* out       = (float*)d_out;
  float* out_logp  = out;
  float* out_value = out + 262144;
  float* out_h     = out + 266240;
  float* out_c     = out + 1314816;
  float* out_loss  = out + 2363392;

  char* ws = (char*)d_ws;
  float* part1  = (float*)(ws + 256);
  float* part2  = (float*)(ws + 1280);
  float* pmn    = (float*)(ws + 2304);
  float* pmx    = (float*)(ws + 18688);
  const size_t MB = 1048576;
  const size_t base = 35072;
  ushort* Wihp    = (ushort*)(ws + base);                    // 512 KB
  ushort* Whhp    = (ushort*)(ws + base + 524288);           // 512 KB
  ushort* WobsT   = (ushort*)(ws + base + 1 * MB);           // 128 KB
  ushort* W1T     = (ushort*)(ws + base + 1 * MB + 131072);
  ushort* W2T     = (ushort*)(ws + base + 1 * MB + 262144);
  ushort* WaTe    = (ushort*)(ws + base + 1 * MB + 393216);  // 128 KB
  float*  bias_ext= (float*) (ws + base + 1 * MB + 524288);  // 512 B
  float*  bias12  = (float*) (ws + base + 1 * MB + 525312);  // 4 KB
  ushort* wab1    = (ushort*)(ws + base + 1 * MB + 532480);  // 8 KB
  ushort* wab2    = (ushort*)(ws + base + 1 * MB + 540672);  // 8 KB
  ushort* enc_bf  = (ushort*)(ws + base + 2 * MB);           // 2 MB
  ushort* h_bf    = (ushort*)(ws + base + 4 * MB);           // 2 MB
  ushort* comm_q1 = (ushort*)(ws + base + 6 * MB);           // 2 MB
  ushort* comm_q2 = (ushort*)(ws + base + 8 * MB);           // 2 MB
  ushort* comm2_bf= (ushort*)(ws + base + 10 * MB);          // 2 MB
  float*  h1      = (float*) (ws + base + 12 * MB);          // 4 MB
  float*  comm1e  = (float*) (ws + base + 16 * MB);          // 4 MB
  float*  h2b     = (float*) (ws + base + 20 * MB);          // 4 MB
  size_t so = base + 24 * MB;
  auto alloc = [&](size_t bytes) { size_t r = so; so += (bytes + 255) & ~255ull; return (char*)ws + r; };
  float* ci1    = (float*)alloc(4 * 4096 * 4);
  float* cj1    = (float*)alloc(4 * 4096 * 4);
  unsigned* skey1 = (unsigned*)alloc(4 * 4096 * 4);
  float* sc1    = (float*)alloc(4 * 4096 * 4);
  int*   pm1    = (int*)  alloc(4 * 4096 * 4);
  float* cku1   = (float*)alloc(4 * 64 * 64 * 4);
  float* ckv1   = (float*)alloc(4 * 64 * 64 * 4);
  float* ckus1  = (float*)alloc(4 * 64 * 4);
  float* ckvs1  = (float*)alloc(4 * 64 * 4);
  float* sufU1  = (float*)alloc(4 * 65 * 64 * 4);
  float* prefV1 = (float*)alloc(4 * 65 * 64 * 4);
  float* sufUs1 = (float*)alloc(4 * 65 * 4);
  float* prefVs1= (float*)alloc(4 * 65 * 4);
  float* ci2    = (float*)alloc(4096 * 4);
  float* cj2    = (float*)alloc(4096 * 4);
  unsigned* skey2 = (unsigned*)alloc(4096 * 4);
  float* sc2    = (float*)alloc(4096 * 4);
  int*   pm2    = (int*)  alloc(4096 * 4);
  float* cku2   = (float*)alloc(64 * 256 * 4);
  float* ckv2   = (float*)alloc(64 * 256 * 4);
  float* ckus2  = (float*)alloc(64 * 4);
  float* ckvs2  = (float*)alloc(64 * 4);
  float* sufU2  = (float*)alloc(65 * 256 * 4);
  float* prefV2 = (float*)alloc(65 * 256 * 4);
  float* sufUs2 = (float*)alloc(65 * 4);
  float* prefVs2= (float*)alloc(65 * 4);
  float* PUl    = (float*)alloc(4 * 4096 * 64 * 4);
  float* PVl    = (float*)alloc(4 * 4096 * 64 * 4);
  float* dUl    = (float*)alloc(4 * 4096 * 4);
  float* dVl    = (float*)alloc(4 * 4096 * 4);

  const dim3 b256(256);
  const int N4 = 262144;

  prep_kernel<<<dim3(997), b256, 0, stream>>>(
      Wih, Wihp, Whh, Whhp, Wobs, WobsT, W1, W1T, W2, W2T,
      Wa, Wv, ba, bv, bih, bhh, WaTe, bias_ext, bias12,
      ai1, aj1, ai2, aj2, wab1, wab2);
  enc_gemm<<<dim3(4, 64), b256, 0, stream>>>(obs, WobsT, bobs, enc_bf);
  gates_lstm_kernel<<<dim3(8, 32), b256, 0, stream>>>(
      enc_bf, Wihp, h0, Whhp, bias12, c0, out_h, out_c, h_bf, pmn, pmx);
  quant_kernel<<<dim3(256), b256, 0, stream>>>(
      (const float4*)out_h, comm_q1, N4, pmn, pmx, 256, part1);
  // ---- GAT1 ----
  gat_feat_kernel<4><<<dim3(320), b256, 0, stream>>>(
      comm_q1, W1T, wab1, h1, ci1, cj1);
  rank_sort_kernel<<<dim3(256), dim3(1024), 0, stream>>>(cj1, skey1, sc1, pm1);
  local_scan1<<<dim3(256), dim3(128), 0, stream>>>(h1, sc1, pm1,
      PUl, PVl, dUl, dVl, cku1, ckv1, ckus1, ckvs1);
  prefix1_kernel<<<dim3(4), dim3(64), 0, stream>>>(cku1, ckv1, ckus1, ckvs1,
                                                   sufU1, prefV1, sufUs1, prefVs1);
  combine1_kernel<<<dim3(4096), b256, 0, stream>>>(ci1, skey1, sc1,
      sufU1, prefV1, sufUs1, prefVs1, PUl, PVl, dUl, dVl, b1, comm1e, pmn, pmx);
  quant_kernel<<<dim3(256), b256, 0, stream>>>(
      (const float4*)comm1e, comm_q2, N4, pmn, pmx, 4096, part2);
  // ---- GAT2 ----
  gat_feat_kernel<1><<<dim3(320), b256, 0, stream>>>(
      comm_q2, W2T, wab2, h2b, ci2, cj2);
  rank_sort_kernel<<<dim3(64), dim3(1024), 0, stream>>>(cj2, skey2, sc2, pm2);
  local_scan2<<<dim3(2, 64), b256, 0, stream>>>(h2b, sc2, pm2,
      PUl, PVl, dUl, dVl, cku2, ckv2, ckus2, ckvs2);
  prefix2_kernel<<<dim3(1), b256, 0, stream>>>(cku2, ckv2, ckus2, ckvs2,
                                               sufU2, prefV2, sufUs2, prefVs2);
  combine2_kernel<<<dim3(4096), b256, 0, stream>>>(ci2, skey2, sc2,
      sufU2, prefV2, sufUs2, prefVs2, PUl, PVl, dUl, dVl, b2, comm2_bf);
  // ---- heads (fused log-softmax + value + loss) ----
  heads_kernel<<<dim3(64), b256, 0, stream>>>(
      h_bf, comm2_bf, WaTe, bias_ext, out_logp, out_value, part1, part2, out_loss);
}

// Round 12
// 245.362 us; speedup vs baseline: 3.0609x; 1.0296x over previous
//
#include <hip/hip_runtime.h>
#include <math.h>

typedef __attribute__((ext_vector_type(8))) short short8;
typedef __attribute__((ext_vector_type(4))) float floatx4;

__device__ __forceinline__ ushort f2b(float f) {
  unsigned u = __float_as_uint(f);
  unsigned r = u + 0x7FFFu + ((u >> 16) & 1u);
  return (ushort)(r >> 16);
}
__device__ __forceinline__ unsigned encf(float f) {
  unsigned u = __float_as_uint(f);
  return (u & 0x80000000u) ? ~u : (u | 0x80000000u);
}

// ====== prep: permuted Wih/Whh conversion, transposes, WaTe, biases, wab ======
// Gate-col permutation: dest col c -> orig row gate*256 + d, where
// gate=(c>>4)&3, d=(c>>6)*16 + (c&15). (64-col block = [i|f|g|o] x 16 units)
__global__ __launch_bounds__(256) void prep_kernel(
    const float* __restrict__ Wih, ushort* __restrict__ Wihp,
    const float* __restrict__ Whh, ushort* __restrict__ Whhp,
    const float* __restrict__ Wobs, ushort* __restrict__ WobsT,
    const float* __restrict__ W1, ushort* __restrict__ W1T,
    const float* __restrict__ W2, ushort* __restrict__ W2T,
    const float* __restrict__ Wa, const float* __restrict__ Wv,
    const float* __restrict__ ba, const float* __restrict__ bv,
    const float* __restrict__ bih, const float* __restrict__ bhh,
    ushort* __restrict__ WaTe, float* __restrict__ bias_ext, float* __restrict__ bias12,
    const float* __restrict__ ai1, const float* __restrict__ aj1,
    const float* __restrict__ ai2, const float* __restrict__ aj2,
    ushort* __restrict__ wab1, ushort* __restrict__ wab2)
{
  __shared__ float tile[32][33];
  const int bid = blockIdx.x;
  const int tid = threadIdx.x;
  if (bid < 512) {
    const int i = bid * 256 + tid;
    const int half = i >> 16;            // 0 = Wih, 1 = Whh
    const int ii = i & 65535;
    const int pr = ii >> 6, k4 = ii & 63;
    const int orow = ((pr >> 4) & 3) * 256 + (pr >> 6) * 16 + (pr & 15);
    const float* s = half ? Whh : Wih;
    ushort* d = half ? Whhp : Wihp;
    const float4 v = *(const float4*)(s + (size_t)orow * 256 + k4 * 4);
    ushort4 o; o.x = f2b(v.x); o.y = f2b(v.y); o.z = f2b(v.z); o.w = f2b(v.w);
    *(ushort4*)(d + (size_t)pr * 256 + k4 * 4) = o;
  } else if (bid < 704) {
    const int t = bid - 512;
    const int mat = t >> 6, sub = t & 63;
    const float* in = mat == 0 ? Wobs : (mat == 1 ? W1 : W2);
    ushort* outp = mat == 0 ? WobsT : (mat == 1 ? W1T : W2T);
    const int c0 = (sub & 7) * 32, r0 = (sub >> 3) * 32;
    const int tx = tid & 31, ty = tid >> 5;
    #pragma unroll
    for (int p = 0; p < 32; p += 8)
      tile[ty + p][tx] = in[(size_t)(r0 + ty + p) * 256 + c0 + tx];
    __syncthreads();
    #pragma unroll
    for (int p = 0; p < 32; p += 8)
      outp[(size_t)(c0 + ty + p) * 256 + r0 + tx] = f2b(tile[tx][ty + p]);
  } else if (bid < 965) {
    const int idx = (bid - 704) * 256 + tid;
    if (idx < 65536) {
      const int n = idx >> 9, k = idx & 511;
      const float v = n < 64 ? Wa[(size_t)k * 64 + n] : (n == 64 ? Wv[k] : 0.0f);
      WaTe[idx] = f2b(v);
    } else if (idx < 65536 + 128) {
      const int n = idx - 65536;
      bias_ext[n] = n < 64 ? ba[n] : (n == 64 ? bv[0] : 0.0f);
    } else if (idx < 65536 + 128 + 1024) {
      const int pc = idx - 65536 - 128;
      const int orow = ((pc >> 4) & 3) * 256 + (pc >> 6) * 16 + (pc & 15);
      bias12[pc] = bih[orow] + bhh[orow];
    }
  } else if (bid < 981) {
    // wab1[16][256]: c<4 -> W1^T ai1 head c ; c in [4,8) -> W1^T aj1 ; else 0
    const int c = bid - 965;
    const int k = tid;
    float val = 0.0f;
    if (c < 8) {
      const int h = c & 3;
      const float* av = (c < 4) ? ai1 : aj1;
      for (int g = 0; g < 64; ++g)
        val += W1[(size_t)k * 256 + h * 64 + g] * av[h * 64 + g];
    }
    wab1[c * 256 + k] = f2b(val);
  } else {
    // wab2[16][256]: c==0 -> W2^T ai2 ; c==1 -> W2^T aj2 ; else 0
    const int c = bid - 981;
    const int k = tid;
    float val = 0.0f;
    if (c < 2) {
      const float* av = (c == 0) ? ai2 : aj2;
      for (int g = 0; g < 256; ++g)
        val += W2[(size_t)k * 256 + g] * av[g];
    }
    wab2[c * 256 + k] = f2b(val);
  }
}

// ===== enc GEMM: enc_bf = bf16(obs @ WobsT^T + bobs); A fp32 converted in staging =====
__global__ __launch_bounds__(256) void enc_gemm(
    const float* __restrict__ obs, const ushort* __restrict__ WobsT,
    const float* __restrict__ bobs, ushort* __restrict__ enc_bf)
{
  constexpr int LDT = 40;
  __shared__ __align__(16) ushort As[64 * LDT];
  __shared__ __align__(16) ushort Bs[64 * LDT];
  const int tid = threadIdx.x;
  const int wave = tid >> 6, lane = tid & 63;
  const int wr = wave >> 1, wc = wave & 1;
  const int m0 = blockIdx.y * 64, n0 = blockIdx.x * 64;
  floatx4 acc[2][2] = {};
  const int r = tid >> 2, kq = tid & 3;
  const int lm = lane & 15, lq = lane >> 4;
  for (int k0 = 0; k0 < 256; k0 += 32) {
    {
      const float* s = &obs[(size_t)(m0 + r) * 256 + k0 + kq * 8];
      const float4 a = *(const float4*)s;
      const float4 b = *(const float4*)(s + 4);
      ushort4 o1, o2;
      o1.x = f2b(a.x); o1.y = f2b(a.y); o1.z = f2b(a.z); o1.w = f2b(a.w);
      o2.x = f2b(b.x); o2.y = f2b(b.y); o2.z = f2b(b.z); o2.w = f2b(b.w);
      *(ushort4*)&As[r * LDT + kq * 8] = o1;
      *(ushort4*)&As[r * LDT + kq * 8 + 4] = o2;
      *(float4*)&Bs[r * LDT + kq * 8] =
          *(const float4*)&WobsT[(size_t)(n0 + r) * 256 + k0 + kq * 8];
    }
    __syncthreads();
    short8 af[2], bfr[2];
    #pragma unroll
    for (int i = 0; i < 2; ++i)
      af[i] = *(const short8*)&As[(wr * 32 + i * 16 + lm) * LDT + lq * 8];
    #pragma unroll
    for (int j = 0; j < 2; ++j)
      bfr[j] = *(const short8*)&Bs[(wc * 32 + j * 16 + lm) * LDT + lq * 8];
    #pragma unroll
    for (int i = 0; i < 2; ++i)
      #pragma unroll
      for (int j = 0; j < 2; ++j)
        acc[i][j] = __builtin_amdgcn_mfma_f32_16x16x32_bf16(af[i], bfr[j], acc[i][j], 0, 0, 0);
    __syncthreads();
  }
  #pragma unroll
  for (int i = 0; i < 2; ++i)
    #pragma unroll
    for (int j = 0; j < 2; ++j) {
      const int col = n0 + wc * 32 + j * 16 + lm;
      const float badd = bobs[col];
      #pragma unroll
      for (int t = 0; t < 4; ++t) {
        const int row = m0 + wr * 32 + i * 16 + lq * 4 + t;
        enc_bf[(size_t)row * 256 + col] = f2b(acc[i][j][t] + badd);
      }
    }
}

// ===== fused gates GEMM (gate-permuted cols) + register LSTM + minmax =====
// BM=64, BN=64: grid (16, 64) = 1024 blocks (4/CU). Wave = 16-row group,
// j-tile = gate. A: enc_bf (k<256) then h0 fp32 (converted in staging).
__global__ __launch_bounds__(256) void gates_lstm_kernel(
    const ushort* __restrict__ enc_bf, const ushort* __restrict__ Wihp,
    const float* __restrict__ h0, const ushort* __restrict__ Whhp,
    const float* __restrict__ bias12p, const float* __restrict__ c0,
    float* __restrict__ h_out, float* __restrict__ c_out, ushort* __restrict__ h_bf,
    float* __restrict__ pmn, float* __restrict__ pmx)
{
  constexpr int LDT = 40;
  __shared__ __align__(16) ushort As[64 * LDT];
  __shared__ __align__(16) ushort Bs[64 * LDT];
  __shared__ float smn[4], smx[4];
  const int tid = threadIdx.x;
  const int wave = tid >> 6, lane = tid & 63;
  const int m0 = blockIdx.y * 64, n0 = blockIdx.x * 64;
  floatx4 acc[4] = {};
  const int r = tid >> 2, kq = tid & 3;
  const int lm = lane & 15, lq = lane >> 4;
  for (int k0 = 0; k0 < 512; k0 += 32) {
    const ushort* B = (k0 < 256) ? Wihp : Whhp;
    const int kk = (k0 < 256) ? k0 : k0 - 256;
    if (k0 < 256) {
      *(float4*)&As[r * LDT + kq * 8] =
          *(const float4*)&enc_bf[(size_t)(m0 + r) * 256 + kk + kq * 8];
    } else {
      const float* s = &h0[(size_t)(m0 + r) * 256 + kk + kq * 8];
      const float4 a = *(const float4*)s;
      const float4 b = *(const float4*)(s + 4);
      ushort4 o1, o2;
      o1.x = f2b(a.x); o1.y = f2b(a.y); o1.z = f2b(a.z); o1.w = f2b(a.w);
      o2.x = f2b(b.x); o2.y = f2b(b.y); o2.z = f2b(b.z); o2.w = f2b(b.w);
      *(ushort4*)&As[r * LDT + kq * 8] = o1;
      *(ushort4*)&As[r * LDT + kq * 8 + 4] = o2;
    }
    *(float4*)&Bs[r * LDT + kq * 8] =
        *(const float4*)&B[(size_t)(n0 + r) * 256 + kk + kq * 8];
    __syncthreads();
    const short8 af = *(const short8*)&As[(wave * 16 + lm) * LDT + lq * 8];
    short8 bfr[4];
    #pragma unroll
    for (int j = 0; j < 4; ++j)
      bfr[j] = *(const short8*)&Bs[(j * 16 + lm) * LDT + lq * 8];
    #pragma unroll
    for (int j = 0; j < 4; ++j)
      acc[j] = __builtin_amdgcn_mfma_f32_16x16x32_bf16(af, bfr[j], acc[j], 0, 0, 0);
    __syncthreads();
  }
  // register LSTM epilogue: lane owns unit d = bx*16+lm, j = gate
  const int d = blockIdx.x * 16 + lm;
  float b4[4];
  #pragma unroll
  for (int j = 0; j < 4; ++j) b4[j] = bias12p[n0 + j * 16 + lm];
  float mnl = 3.0e38f, mxl = -3.0e38f;
  #pragma unroll
  for (int t = 0; t < 4; ++t) {
    const int row = m0 + wave * 16 + lq * 4 + t;
    const size_t off = (size_t)row * 256 + d;
    const float gi = acc[0][t] + b4[0];
    const float gf = acc[1][t] + b4[1];
    const float gg = acc[2][t] + b4[2];
    const float go = acc[3][t] + b4[3];
    const float cc = c0[off];
    const float si = 1.0f / (1.0f + expf(-gi));
    const float sf = 1.0f / (1.0f + expf(-gf));
    const float so = 1.0f / (1.0f + expf(-go));
    const float c2 = sf * cc + si * tanhf(gg);
    const float h2 = so * tanhf(c2);
    h_out[off] = h2;
    c_out[off] = c2;
    h_bf[off] = f2b(h2);
    mnl = fminf(mnl, h2); mxl = fmaxf(mxl, h2);
  }
  #pragma unroll
  for (int o = 32; o > 0; o >>= 1) {
    mnl = fminf(mnl, __shfl_xor(mnl, o));
    mxl = fmaxf(mxl, __shfl_xor(mxl, o));
  }
  if (lane == 0) { smn[wave] = mnl; smx[wave] = mxl; }
  __syncthreads();
  if (tid == 0) {
    const int bid = blockIdx.y * 16 + blockIdx.x;
    pmn[bid] = fminf(fminf(smn[0], smn[1]), fminf(smn[2], smn[3]));
    pmx[bid] = fmaxf(fmaxf(smx[0], smx[1]), fmaxf(smx[2], smx[3]));
  }
}

// === fake-quant (fused global min/max from partials) -> bf16 + loss partial ===
__global__ __launch_bounds__(256) void quant_kernel(
    const float4* __restrict__ x, ushort* __restrict__ q, int n4,
    const float* __restrict__ pmn, const float* __restrict__ pmx, int np,
    float* __restrict__ part)
{
  __shared__ float smn[4], smx[4], sl[4], bmn, bmx;
  float mn = 3.0e38f, mx = -3.0e38f;
  for (int i = threadIdx.x; i < np; i += 256) {
    mn = fminf(mn, pmn[i]); mx = fmaxf(mx, pmx[i]);
  }
  #pragma unroll
  for (int o = 32; o > 0; o >>= 1) {
    mn = fminf(mn, __shfl_xor(mn, o));
    mx = fmaxf(mx, __shfl_xor(mx, o));
  }
  if ((threadIdx.x & 63) == 0) { smn[threadIdx.x >> 6] = mn; smx[threadIdx.x >> 6] = mx; }
  __syncthreads();
  if (threadIdx.x == 0) {
    bmn = fminf(fminf(smn[0], smn[1]), fminf(smn[2], smn[3]));
    bmx = fmaxf(fmaxf(smx[0], smx[1]), fmaxf(smx[2], smx[3]));
  }
  __syncthreads();
  mn = bmn; mx = bmx;
  if (mn == mx) { mn -= 0.01f; mx += 0.01f; }
  const float scale = (mx - mn) / 255.0f;
  const float zp = rintf(-mn / scale);
  float lsum = 0.0f;
  for (int idx = blockIdx.x * 256 + threadIdx.x; idx < n4; idx += gridDim.x * 256) {
    const float4 t = x[idx];
    float d0, d1, d2, d3;
    { float qq = fminf(fmaxf(rintf(t.x / scale + zp), 0.0f), 255.0f);
      d0 = (qq - zp) * scale; lsum += log2f(510.0f * fabsf(d0) + 1.0f); }
    { float qq = fminf(fmaxf(rintf(t.y / scale + zp), 0.0f), 255.0f);
      d1 = (qq - zp) * scale; lsum += log2f(510.0f * fabsf(d1) + 1.0f); }
    { float qq = fminf(fmaxf(rintf(t.z / scale + zp), 0.0f), 255.0f);
      d2 = (qq - zp) * scale; lsum += log2f(510.0f * fabsf(d2) + 1.0f); }
    { float qq = fminf(fmaxf(rintf(t.w / scale + zp), 0.0f), 255.0f);
      d3 = (qq - zp) * scale; lsum += log2f(510.0f * fabsf(d3) + 1.0f); }
    ushort4 o; o.x = f2b(d0); o.y = f2b(d1); o.z = f2b(d2); o.w = f2b(d3);
    *(ushort4*)(q + (size_t)idx * 4) = o;
  }
  #pragma unroll
  for (int o = 32; o > 0; o >>= 1) lsum += __shfl_xor(lsum, o);
  if ((threadIdx.x & 63) == 0) sl[threadIdx.x >> 6] = lsum;
  __syncthreads();
  if (threadIdx.x == 0) part[blockIdx.x] = sl[0] + sl[1] + sl[2] + sl[3];
}

// ==== GAT features: blocks 0..255 = h GEMM (fp32 out), 256..319 = ci/cj MFMA ====
template<int HN>
__global__ __launch_bounds__(256) void gat_feat_kernel(
    const ushort* __restrict__ Aq, const ushort* __restrict__ WT,
    const ushort* __restrict__ wab,
    float* __restrict__ hout, float* __restrict__ ci, float* __restrict__ cj)
{
  constexpr int LDT = 40;
  __shared__ __align__(16) ushort As[64 * LDT];
  __shared__ __align__(16) ushort Bs[64 * LDT];
  const int bid = blockIdx.x;
  const int tid = threadIdx.x;
  const int wave = tid >> 6, lane = tid & 63;
  const int lm = lane & 15, lq = lane >> 4;
  const int r = tid >> 2, kq = tid & 3;
  if (bid < 256) {
    const int bx = bid & 3, by = bid >> 2;
    const int m0 = by * 64, n0 = bx * 64;
    const int wr = wave >> 1, wc = wave & 1;
    floatx4 acc[2][2] = {};
    for (int k0 = 0; k0 < 256; k0 += 32) {
      *(float4*)&As[r * LDT + kq * 8] =
          *(const float4*)&Aq[(size_t)(m0 + r) * 256 + k0 + kq * 8];
      *(float4*)&Bs[r * LDT + kq * 8] =
          *(const float4*)&WT[(size_t)(n0 + r) * 256 + k0 + kq * 8];
      __syncthreads();
      short8 af[2], bfr[2];
      #pragma unroll
      for (int i = 0; i < 2; ++i)
        af[i] = *(const short8*)&As[(wr * 32 + i * 16 + lm) * LDT + lq * 8];
      #pragma unroll
      for (int j = 0; j < 2; ++j)
        bfr[j] = *(const short8*)&Bs[(wc * 32 + j * 16 + lm) * LDT + lq * 8];
      #pragma unroll
      for (int i = 0; i < 2; ++i)
        #pragma unroll
        for (int j = 0; j < 2; ++j)
          acc[i][j] = __builtin_amdgcn_mfma_f32_16x16x32_bf16(af[i], bfr[j], acc[i][j], 0, 0, 0);
      __syncthreads();
    }
    #pragma unroll
    for (int i = 0; i < 2; ++i)
      #pragma unroll
      for (int j = 0; j < 2; ++j) {
        const int col = n0 + wc * 32 + j * 16 + lm;
        #pragma unroll
        for (int t = 0; t < 4; ++t) {
          const int row = m0 + wr * 32 + i * 16 + lq * 4 + t;
          hout[(size_t)row * 256 + col] = acc[i][j][t];
        }
      }
  } else {
    // ci/cj: [64 rows] x [16 cols] MFMA against wab
    const int m0 = (bid - 256) * 64;
    floatx4 acc = {0.f, 0.f, 0.f, 0.f};
    for (int k0 = 0; k0 < 256; k0 += 32) {
      *(float4*)&As[r * LDT + kq * 8] =
          *(const float4*)&Aq[(size_t)(m0 + r) * 256 + k0 + kq * 8];
      if (r < 16)
        *(float4*)&Bs[r * LDT + kq * 8] =
            *(const float4*)&wab[(size_t)r * 256 + k0 + kq * 8];
      __syncthreads();
      const short8 af = *(const short8*)&As[(wave * 16 + lm) * LDT + lq * 8];
      const short8 bf = *(const short8*)&Bs[lm * LDT + lq * 8];
      acc = __builtin_amdgcn_mfma_f32_16x16x32_bf16(af, bf, acc, 0, 0, 0);
      __syncthreads();
    }
    #pragma unroll
    for (int t = 0; t < 4; ++t) {
      const int row = m0 + wave * 16 + lq * 4 + t;
      if (lm < HN) ci[lm * 4096 + row] = acc[t];
      else if (lm < 2 * HN) cj[(lm - HN) * 4096 + row] = acc[t];
    }
  }
}

// ====== rank sort, u32 keys (top-20 value bits | 12-bit idx) ======
__global__ __launch_bounds__(1024) void rank_sort_kernel(
    const float* __restrict__ c, unsigned* __restrict__ skey,
    float* __restrict__ sc, int* __restrict__ pm)
{
  __shared__ unsigned lk[4096];
  __shared__ int scnt[16][64];
  const int head = blockIdx.x >> 6;
  const int seg = blockIdx.x & 63;
  const float* ch = c + head * 4096;
  for (int idx = threadIdx.x; idx < 4096; idx += 1024)
    lk[idx] = (encf(ch[idx]) & 0xFFFFF000u) | (unsigned)idx;
  __syncthreads();
  const int jl = threadIdx.x & 63;
  const int kg = threadIdx.x >> 6;
  const unsigned my = lk[seg * 64 + jl];
  int cnt = 0;
  const int k0 = kg * 256;
  #pragma unroll 8
  for (int k = k0; k < k0 + 256; ++k)
    cnt += lk[k] < my ? 1 : 0;
  scnt[kg][jl] = cnt;
  __syncthreads();
  if (threadIdx.x < 64) {
    int rank = 0;
    #pragma unroll
    for (int g = 0; g < 16; ++g) rank += scnt[g][threadIdx.x];
    const unsigned kk = lk[seg * 64 + threadIdx.x];
    const int jj = (int)(kk & 0xFFFu);
    skey[head * 4096 + rank] = kk;
    sc[head * 4096 + rank] = ch[jj];
    pm[head * 4096 + rank] = jj;
  }
}

// ======= local scan (GAT1): 2 waves/block, wave0=PV asc, wave1=PU desc =======
__global__ __launch_bounds__(128) void local_scan1(
    const float* __restrict__ h1, const float* __restrict__ sc, const int* __restrict__ pm,
    float* __restrict__ PUl, float* __restrict__ PVl,
    float* __restrict__ dUl, float* __restrict__ dVl,
    float* __restrict__ cku, float* __restrict__ ckv,
    float* __restrict__ ckus, float* __restrict__ ckvs)
{
  const int head = blockIdx.x >> 6;
  const int chunk = blockIdx.x & 63;
  const int wave = threadIdx.x >> 6;
  const int lane = threadIdx.x & 63;
  const float cmax = sc[head * 4096 + 4095];
  const int base = head * 4096 + chunk * 64;
  const float cv = sc[base + lane];
  const float u = expf(cv - cmax);
  const float v = expf(0.2f * (cv - cmax));
  const int myj = pm[base + lane];
  const float* hrow = h1 + head * 64 + lane;
  if (wave == 0) {
    float iu = u, iv = v;
    #pragma unroll
    for (int o = 1; o < 64; o <<= 1) {
      const float tu = __shfl_up(iu, o), tv = __shfl_up(iv, o);
      if (lane >= o) { iu += tu; iv += tv; }
    }
    const float totU = __shfl(iu, 63), totV = __shfl(iv, 63);
    dVl[base + lane] = iv - v;
    dUl[base + lane] = totU - (iu - u);
    if (lane == 0) { ckus[head * 64 + chunk] = totU; ckvs[head * 64 + chunk] = totV; }
    float accV = 0.f;
    #pragma unroll 16
    for (int k = 0; k < 64; ++k) {
      const float vk = __shfl(v, k);
      const int j = __shfl(myj, k);
      PVl[(size_t)(base + k) * 64 + lane] = accV;
      accV += vk * hrow[(size_t)j * 256];
    }
    ckv[(head * 64 + chunk) * 64 + lane] = accV;
  } else {
    float accU = 0.f;
    #pragma unroll 16
    for (int k = 63; k >= 0; --k) {
      const float uk = __shfl(u, k);
      const int j = __shfl(myj, k);
      accU += uk * hrow[(size_t)j * 256];
      PUl[(size_t)(base + k) * 64 + lane] = accU;
    }
    cku[(head * 64 + chunk) * 64 + lane] = accU;
  }
}

// === local scan (GAT2, g=256): grid (colgrp=2, chunk=64); waves 0-1 PV, 2-3 PU ===
__global__ __launch_bounds__(256) void local_scan2(
    const float* __restrict__ h2, const float* __restrict__ sc, const int* __restrict__ pm,
    float* __restrict__ PUl, float* __restrict__ PVl,
    float* __restrict__ dUl, float* __restrict__ dVl,
    float* __restrict__ cku, float* __restrict__ ckv,
    float* __restrict__ ckus, float* __restrict__ ckvs)
{
  __shared__ float su[64], sv[64];
  __shared__ int sj[64];
  const int chunk = blockIdx.y;
  const int colgrp = blockIdx.x;
  const int tid = threadIdx.x;
  const int wave = tid >> 6, lane = tid & 63;
  const float cmax = sc[4095];
  const int base = chunk * 64;
  if (tid < 64) {
    const float cv = sc[base + tid];
    const float u = expf(cv - cmax);
    const float v = expf(0.2f * (cv - cmax));
    su[tid] = u; sv[tid] = v; sj[tid] = pm[base + tid];
    if (colgrp == 0) {
      float iu = u, iv = v;
      #pragma unroll
      for (int o = 1; o < 64; o <<= 1) {
        const float tu = __shfl_up(iu, o), tv = __shfl_up(iv, o);
        if (lane >= o) { iu += tu; iv += tv; }
      }
      const float totU = __shfl(iu, 63), totV = __shfl(iv, 63);
      dVl[base + lane] = iv - v;
      dUl[base + lane] = totU - (iu - u);
      if (lane == 0) { ckus[chunk] = totU; ckvs[chunk] = totV; }
    }
  }
  __syncthreads();
  const int col = colgrp * 128 + (wave & 1) * 64 + lane;
  if (wave < 2) {
    float accV = 0.f;
    #pragma unroll 16
    for (int k = 0; k < 64; ++k) {
      PVl[(size_t)(base + k) * 256 + col] = accV;
      accV += sv[k] * h2[(size_t)sj[k] * 256 + col];
    }
    ckv[chunk * 256 + col] = accV;
  } else {
    float accU = 0.f;
    #pragma unroll 16
    for (int k = 63; k >= 0; --k) {
      accU += su[k] * h2[(size_t)sj[k] * 256 + col];
      PUl[(size_t)(base + k) * 256 + col] = accU;
    }
    cku[chunk * 256 + col] = accU;
  }
}

// ======= chunk prefix/suffix: lane=col (coalesced), serial chunk loop =======
__global__ __launch_bounds__(64) void prefix1_kernel(
    const float* __restrict__ cku, const float* __restrict__ ckv,
    const float* __restrict__ ckus, const float* __restrict__ ckvs,
    float* __restrict__ sufU, float* __restrict__ prefV,
    float* __restrict__ sufUs, float* __restrict__ prefVs)
{
  const int head = blockIdx.x, lane = threadIdx.x;
  float acc = 0.f;
  for (int c = 0; c < 64; ++c) {
    prefV[(head * 65 + c) * 64 + lane] = acc;
    acc += ckv[(head * 64 + c) * 64 + lane];
  }
  prefV[(head * 65 + 64) * 64 + lane] = acc;
  acc = 0.f;
  sufU[(head * 65 + 64) * 64 + lane] = 0.f;
  for (int c = 63; c >= 0; --c) {
    acc += cku[(head * 64 + c) * 64 + lane];
    sufU[(head * 65 + c) * 64 + lane] = acc;
  }
  {
    const float vs = ckvs[head * 64 + lane];
    const float us = ckus[head * 64 + lane];
    float iv = vs, iu = us;
    #pragma unroll
    for (int o = 1; o < 64; o <<= 1) {
      const float tv = __shfl_up(iv, o), tu = __shfl_up(iu, o);
      if (lane >= o) { iv += tv; iu += tu; }
    }
    prefVs[head * 65 + lane] = iv - vs;
    const float totU = __shfl(iu, 63);
    sufUs[head * 65 + lane] = totU - iu + us;
    if (lane == 63) {
      prefVs[head * 65 + 64] = iv;
      sufUs[head * 65 + 64] = 0.f;
    }
  }
}

__global__ __launch_bounds__(256) void prefix2_kernel(
    const float* __restrict__ cku, const float* __restrict__ ckv,
    const float* __restrict__ ckus, const float* __restrict__ ckvs,
    float* __restrict__ sufU, float* __restrict__ prefV,
    float* __restrict__ sufUs, float* __restrict__ prefVs)
{
  const int col = threadIdx.x;
  const int lane = col & 63;
  float acc = 0.f;
  for (int c = 0; c < 64; ++c) {
    prefV[c * 256 + col] = acc;
    acc += ckv[c * 256 + col];
  }
  prefV[64 * 256 + col] = acc;
  acc = 0.f;
  sufU[64 * 256 + col] = 0.f;
  for (int c = 63; c >= 0; --c) {
    acc += cku[c * 256 + col];
    sufU[c * 256 + col] = acc;
  }
  if (col < 64) {
    const float vs = ckvs[lane];
    const float us = ckus[lane];
    float iv = vs, iu = us;
    #pragma unroll
    for (int o = 1; o < 64; o <<= 1) {
      const float tv = __shfl_up(iv, o), tu = __shfl_up(iu, o);
      if (lane >= o) { iv += tv; iu += tu; }
    }
    prefVs[lane] = iv - vs;
    const float totU = __shfl(iu, 63);
    sufUs[lane] = totU - iu + us;
    if (lane == 63) { prefVs[64] = iv; sufUs[64] = 0.f; }
  }
}

// ====== GAT1 combine: lookup via u32-key binary search + minmax ======
__global__ __launch_bounds__(256) void combine1_kernel(
    const float* __restrict__ ci, const unsigned* __restrict__ skey,
    const float* __restrict__ sc,
    const float* __restrict__ sufU, const float* __restrict__ prefV,
    const float* __restrict__ sufUs, const float* __restrict__ prefVs,
    const float* __restrict__ PUl, const float* __restrict__ PVl,
    const float* __restrict__ dUl, const float* __restrict__ dVl,
    const float* __restrict__ b1, float* __restrict__ out,
    float* __restrict__ pmn, float* __restrict__ pmx)
{
  const int i = blockIdx.x;
  const int head = threadIdx.x >> 6;
  const int lane = threadIdx.x & 63;
  const unsigned* skh = skey + head * 4096;
  const float civ = ci[head * 4096 + i];
  const float cmax = sc[head * 4096 + 4095];
  const float sarg = civ + cmax;
  const float m = sarg > 0.f ? sarg : 0.2f * sarg;
  const float Af = expf(sarg - m);
  const float Bf = expf(0.2f * sarg - m);
  const unsigned tkey = (encf(-civ) & 0xFFFFF000u) | 0xFFFu;
  int lo = 0, hi = 4096;
  while (lo < hi) {
    const int mid = (lo + hi) >> 1;
    if (skh[mid] > tkey) hi = mid; else lo = mid + 1;
  }
  const int s = lo;
  float accP, accN, dP, dN;
  if (s == 4096) {
    accP = 0.f; dP = 0.f;
    accN = prefV[(head * 65 + 64) * 64 + lane];
    dN = prefVs[head * 65 + 64];
  } else {
    const int cs = s >> 6;
    accP = sufU[(head * 65 + cs + 1) * 64 + lane] + PUl[(size_t)(head * 4096 + s) * 64 + lane];
    accN = prefV[(head * 65 + cs) * 64 + lane] + PVl[(size_t)(head * 4096 + s) * 64 + lane];
    dP = sufUs[head * 65 + cs + 1] + dUl[head * 4096 + s];
    dN = prefVs[head * 65 + cs] + dVl[head * 4096 + s];
  }
  const float num = Af * accP + Bf * accN;
  const float den = Af * dP + Bf * dN;
  const float o = num / den + b1[head * 64 + lane];
  const float oe = o > 0.f ? o : expm1f(o);
  out[(size_t)i * 256 + head * 64 + lane] = oe;
  float mn = oe, mx = oe;
  #pragma unroll
  for (int of = 32; of > 0; of >>= 1) {
    mn = fminf(mn, __shfl_xor(mn, of));
    mx = fmaxf(mx, __shfl_xor(mx, of));
  }
  __shared__ float smn[4], smx[4];
  if (lane == 0) { smn[head] = mn; smx[head] = mx; }
  __syncthreads();
  if (threadIdx.x == 0) {
    pmn[i] = fminf(fminf(smn[0], smn[1]), fminf(smn[2], smn[3]));
    pmx[i] = fmaxf(fmaxf(smx[0], smx[1]), fmaxf(smx[2], smx[3]));
  }
}

// ========= GAT2 combine: lookup via u32-key search, writes bf16 =========
__global__ __launch_bounds__(256) void combine2_kernel(
    const float* __restrict__ ci, const unsigned* __restrict__ skey,
    const float* __restrict__ sc,
    const float* __restrict__ sufU, const float* __restrict__ prefV,
    const float* __restrict__ sufUs, const float* __restrict__ prefVs,
    const float* __restrict__ PUl, const float* __restrict__ PVl,
    const float* __restrict__ dUl, const float* __restrict__ dVl,
    const float* __restrict__ b2, ushort* __restrict__ outb)
{
  const int i = blockIdx.x;
  const int col = threadIdx.x;
  const float civ = ci[i];
  const float cmax = sc[4095];
  const float sarg = civ + cmax;
  const float m = sarg > 0.f ? sarg : 0.2f * sarg;
  const float Af = expf(sarg - m);
  const float Bf = expf(0.2f * sarg - m);
  const unsigned tkey = (encf(-civ) & 0xFFFFF000u) | 0xFFFu;
  int lo = 0, hi = 4096;
  while (lo < hi) {
    const int mid = (lo + hi) >> 1;
    if (skey[mid] > tkey) hi = mid; else lo = mid + 1;
  }
  const int s = lo;
  float accP, accN, dP, dN;
  if (s == 4096) {
    accP = 0.f; dP = 0.f;
    accN = prefV[64 * 256 + col];
    dN = prefVs[64];
  } else {
    const int cs = s >> 6;
    accP = sufU[(cs + 1) * 256 + col] + PUl[(size_t)s * 256 + col];
    accN = prefV[cs * 256 + col] + PVl[(size_t)s * 256 + col];
    dP = sufUs[cs + 1] + dUl[s];
    dN = prefVs[cs] + dVl[s];
  }
  const float num = Af * accP + Bf * accN;
  const float den = Af * dP + Bf * dN;
  outb[(size_t)i * 256 + col] = f2b(num / den + b2[col]);
}

// ==== heads: [h|comm2]@WaTe^T + bias, fused log-softmax + value + loss ====
__global__ __launch_bounds__(256) void heads_kernel(
    const ushort* __restrict__ h_bf, const ushort* __restrict__ comm2_bf,
    const ushort* __restrict__ WaTe, const float* __restrict__ bias_ext,
    float* __restrict__ out_logp, float* __restrict__ out_value,
    const float* __restrict__ p1, const float* __restrict__ p2,
    float* __restrict__ out_loss)
{
  constexpr int LDT = 40;
  __shared__ __align__(16) ushort As[64 * LDT];
  __shared__ __align__(16) ushort Bs[128 * LDT];
  __shared__ float lbuf[64][68];
  const int tid = threadIdx.x;
  const int wave = tid >> 6, lane = tid & 63;
  const int wr = wave >> 1, wc = wave & 1;
  const int m0 = blockIdx.x * 64;
  const int lm = lane & 15, lq = lane >> 4;
  floatx4 acc[2][4] = {};
  const int r = tid >> 2, kq = tid & 3;
  for (int k0 = 0; k0 < 512; k0 += 32) {
    const ushort* Asrc = (k0 < 256) ? h_bf : comm2_bf;
    const int kk = (k0 < 256) ? k0 : k0 - 256;
    *(float4*)&As[r * LDT + kq * 8] =
        *(const float4*)&Asrc[(size_t)(m0 + r) * 256 + kk + kq * 8];
    #pragma unroll
    for (int p = 0; p < 2; ++p) {
      const int rr = r + p * 64;
      *(float4*)&Bs[rr * LDT + kq * 8] =
          *(const float4*)&WaTe[(size_t)rr * 512 + k0 + kq * 8];
    }
    __syncthreads();
    short8 af[2], bfr[4];
    #pragma unroll
    for (int i = 0; i < 2; ++i)
      af[i] = *(const short8*)&As[(wr * 32 + i * 16 + lm) * LDT + lq * 8];
    #pragma unroll
    for (int j = 0; j < 4; ++j)
      bfr[j] = *(const short8*)&Bs[(wc * 64 + j * 16 + lm) * LDT + lq * 8];
    #pragma unroll
    for (int i = 0; i < 2; ++i)
      #pragma unroll
      for (int j = 0; j < 4; ++j)
        acc[i][j] = __builtin_amdgcn_mfma_f32_16x16x32_bf16(af[i], bfr[j], acc[i][j], 0, 0, 0);
    __syncthreads();
  }
  #pragma unroll
  for (int i = 0; i < 2; ++i)
    #pragma unroll
    for (int j = 0; j < 4; ++j) {
      const int col = wc * 64 + j * 16 + lm;
      if (col < 65) {
        const float badd = bias_ext[col];
        #pragma unroll
        for (int t = 0; t < 4; ++t)
          lbuf[wr * 32 + i * 16 + lq * 4 + t][col] = acc[i][j][t] + badd;
      }
    }
  __syncthreads();
  for (int rr2 = 0; rr2 < 16; ++rr2) {
    const int row = wave * 16 + rr2;
    const float x = lbuf[row][lane];
    float mx = x;
    #pragma unroll
    for (int o = 32; o > 0; o >>= 1) mx = fmaxf(mx, __shfl_xor(mx, o));
    float e = expf(x - mx);
    #pragma unroll
    for (int o = 32; o > 0; o >>= 1) e += __shfl_xor(e, o);
    out_logp[(size_t)(m0 + row) * 64 + lane] = x - mx - logf(e);
    if (lane == 0) out_value[m0 + row] = lbuf[row][64];
  }
  if (blockIdx.x == 0 && wave == 0) {
    float s = 0.f;
    #pragma unroll
    for (int k = 0; k < 4; ++k) s += p1[lane + k * 64] + p2[lane + k * 64];
    #pragma unroll
    for (int o = 32; o > 0; o >>= 1) s += __shfl_xor(s, o);
    if (lane == 0) out_loss[0] = s;
  }
}

// ============================ launch ============================
extern "C" void kernel_launch(void* const* d_in, const int* in_sizes, int n_in,
                              void* d_out, int out_size, void* d_ws, size_t ws_size,
                              hipStream_t stream) {
  const float* obs  = (const float*)d_in[0];
  const float* h0   = (const float*)d_in[1];
  const float* c0   = (const float*)d_in[2];
  const float* Wobs = (const float*)d_in[3];
  const float* bobs = (const float*)d_in[4];
  const float* Wih  = (const float*)d_in[5];
  const float* Whh  = (const float*)d_in[6];
  const float* bih  = (const float*)d_in[7];
  const float* bhh  = (const float*)d_in[8];
  const float* W1   = (const float*)d_in[9];
  const float* ai1  = (const float*)d_in[10];
  const float* aj1  = (const float*)d_in[11];
  const float* b1   = (const float*)d_in[12];
  const float* W2   = (const float*)d_in[13];
  const float* ai2  = (const float*)d_in[14];
  const float* aj2  = (const float*)d_in[15];
  const float* b2   = (const float*)d_in[16];
  const float* Wv   = (const float*)d_in[17];
  const float* bv   = (const float*)d_in[18];
  const float* Wa   = (const float*)d_in[19];
  const float* ba   = (const float*)d_in[20];

  float* out       = (float*)d_out;
  float* out_logp  = out;
  float* out_value = out + 262144;
  float* out_h     = out + 266240;
  float* out_c     = out + 1314816;
  float* out_loss  = out + 2363392;

  char* ws = (char*)d_ws;
  float* part1  = (float*)(ws + 256);
  float* part2  = (float*)(ws + 1280);
  float* pmn    = (float*)(ws + 2304);
  float* pmx    = (float*)(ws + 18688);
  const size_t MB = 1048576;
  const size_t base = 35072;
  ushort* Wihp    = (ushort*)(ws + base);                    // 512 KB
  ushort* Whhp    = (ushort*)(ws + base + 524288);           // 512 KB
  ushort* WobsT   = (ushort*)(ws + base + 1 * MB);           // 128 KB
  ushort* W1T     = (ushort*)(ws + base + 1 * MB + 131072);
  ushort* W2T     = (ushort*)(ws + base + 1 * MB + 262144);
  ushort* WaTe    = (ushort*)(ws + base + 1 * MB + 393216);  // 128 KB
  float*  bias_ext= (float*) (ws + base + 1 * MB + 524288);  // 512 B
  float*  bias12  = (float*) (ws + base + 1 * MB + 525312);  // 4 KB
  ushort* wab1    = (ushort*)(ws + base + 1 * MB + 532480);  // 8 KB
  ushort* wab2    = (ushort*)(ws + base + 1 * MB + 540672);  // 8 KB
  ushort* enc_bf  = (ushort*)(ws + base + 2 * MB);           // 2 MB
  ushort* h_bf    = (ushort*)(ws + base + 4 * MB);           // 2 MB
  ushort* comm_q1 = (ushort*)(ws + base + 6 * MB);           // 2 MB
  ushort* comm_q2 = (ushort*)(ws + base + 8 * MB);           // 2 MB
  ushort* comm2_bf= (ushort*)(ws + base + 10 * MB);          // 2 MB
  float*  h1      = (float*) (ws + base + 12 * MB);          // 4 MB
  float*  comm1e  = (float*) (ws + base + 16 * MB);          // 4 MB
  float*  h2b     = (float*) (ws + base + 20 * MB);          // 4 MB
  size_t so = base + 24 * MB;
  auto alloc = [&](size_t bytes) { size_t r = so; so += (bytes + 255) & ~255ull; return (char*)ws + r; };
  float* ci1    = (float*)alloc(4 * 4096 * 4);
  float* cj1    = (float*)alloc(4 * 4096 * 4);
  unsigned* skey1 = (unsigned*)alloc(4 * 4096 * 4);
  float* sc1    = (float*)alloc(4 * 4096 * 4);
  int*   pm1    = (int*)  alloc(4 * 4096 * 4);
  float* cku1   = (float*)alloc(4 * 64 * 64 * 4);
  float* ckv1   = (float*)alloc(4 * 64 * 64 * 4);
  float* ckus1  = (float*)alloc(4 * 64 * 4);
  float* ckvs1  = (float*)alloc(4 * 64 * 4);
  float* sufU1  = (float*)alloc(4 * 65 * 64 * 4);
  float* prefV1 = (float*)alloc(4 * 65 * 64 * 4);
  float* sufUs1 = (float*)alloc(4 * 65 * 4);
  float* prefVs1= (float*)alloc(4 * 65 * 4);
  float* ci2    = (float*)alloc(4096 * 4);
  float* cj2    = (float*)alloc(4096 * 4);
  unsigned* skey2 = (unsigned*)alloc(4096 * 4);
  float* sc2    = (float*)alloc(4096 * 4);
  int*   pm2    = (int*)  alloc(4096 * 4);
  float* cku2   = (float*)alloc(64 * 256 * 4);
  float* ckv2   = (float*)alloc(64 * 256 * 4);
  float* ckus2  = (float*)alloc(64 * 4);
  float* ckvs2  = (float*)alloc(64 * 4);
  float* sufU2  = (float*)alloc(65 * 256 * 4);
  float* prefV2 = (float*)alloc(65 * 256 * 4);
  float* sufUs2 = (float*)alloc(65 * 4);
  float* prefVs2= (float*)alloc(65 * 4);
  float* PUl    = (float*)alloc(4 * 4096 * 64 * 4);
  float* PVl    = (float*)alloc(4 * 4096 * 64 * 4);
  float* dUl    = (float*)alloc(4 * 4096 * 4);
  float* dVl    = (float*)alloc(4 * 4096 * 4);

  const dim3 b256(256);
  const int N4 = 262144;

  prep_kernel<<<dim3(997), b256, 0, stream>>>(
      Wih, Wihp, Whh, Whhp, Wobs, WobsT, W1, W1T, W2, W2T,
      Wa, Wv, ba, bv, bih, bhh, WaTe, bias_ext, bias12,
      ai1, aj1, ai2, aj2, wab1, wab2);
  enc_gemm<<<dim3(4, 64), b256, 0, stream>>>(obs, WobsT, bobs, enc_bf);
  gates_lstm_kernel<<<dim3(16, 64), b256, 0, stream>>>(
      enc_bf, Wihp, h0, Whhp, bias12, c0, out_h, out_c, h_bf, pmn, pmx);
  quant_kernel<<<dim3(256), b256, 0, stream>>>(
      (const float4*)out_h, comm_q1, N4, pmn, pmx, 1024, part1);
  // ---- GAT1 ----
  gat_feat_kernel<4><<<dim3(320), b256, 0, stream>>>(
      comm_q1, W1T, wab1, h1, ci1, cj1);
  rank_sort_kernel<<<dim3(256), dim3(1024), 0, stream>>>(cj1, skey1, sc1, pm1);
  local_scan1<<<dim3(256), dim3(128), 0, stream>>>(h1, sc1, pm1,
      PUl, PVl, dUl, dVl, cku1, ckv1, ckus1, ckvs1);
  prefix1_kernel<<<dim3(4), dim3(64), 0, stream>>>(cku1, ckv1, ckus1, ckvs1,
                                                   sufU1, prefV1, sufUs1, prefVs1);
  combine1_kernel<<<dim3(4096), b256, 0, stream>>>(ci1, skey1, sc1,
      sufU1, prefV1, sufUs1, prefVs1, PUl, PVl, dUl, dVl, b1, comm1e, pmn, pmx);
  quant_kernel<<<dim3(256), b256, 0, stream>>>(
      (const float4*)comm1e, comm_q2, N4, pmn, pmx, 4096, part2);
  // ---- GAT2 ----
  gat_feat_kernel<1><<<dim3(320), b256, 0, stream>>>(
      comm_q2, W2T, wab2, h2b, ci2, cj2);
  rank_sort_kernel<<<dim3(64), dim3(1024), 0, stream>>>(cj2, skey2, sc2, pm2);
  local_scan2<<<dim3(2, 64), b256, 0, stream>>>(h2b, sc2, pm2,
      PUl, PVl, dUl, dVl, cku2, ckv2, ckus2, ckvs2);
  prefix2_kernel<<<dim3(1), b256, 0, stream>>>(cku2, ckv2, ckus2, ckvs2,
                                               sufU2, prefV2, sufUs2, prefVs2);
  combine2_kernel<<<dim3(4096), b256, 0, stream>>>(ci2, skey2, sc2,
      sufU2, prefV2, sufUs2, prefVs2, PUl, PVl, dUl, dVl, b2, comm2_bf);
  // ---- heads (fused log-softmax + value + loss) ----
  heads_kernel<<<dim3(64), b256, 0, stream>>>(
      h_bf, comm2_bf, WaTe, bias_ext, out_logp, out_value, part1, part2, out_loss);
}

// Round 13
// 239.674 us; speedup vs baseline: 3.1335x; 1.0237x over previous
//
#include <hip/hip_runtime.h>
#include <math.h>

typedef __attribute__((ext_vector_type(8))) short short8;
typedef __attribute__((ext_vector_type(4))) float floatx4;

__device__ __forceinline__ ushort f2b(float f) {
  unsigned u = __float_as_uint(f);
  unsigned r = u + 0x7FFFu + ((u >> 16) & 1u);
  return (ushort)(r >> 16);
}
__device__ __forceinline__ unsigned encf(float f) {
  unsigned u = __float_as_uint(f);
  return (u & 0x80000000u) ? ~u : (u | 0x80000000u);
}

// ====== prep: permuted Wih/Whh conversion, transposes, WaTe, biases, wab ======
// Gate-col permutation: dest col c -> orig row gate*256 + d, where
// gate=(c>>4)&3, d=(c>>6)*16 + (c&15). (64-col block = [i|f|g|o] x 16 units)
__global__ __launch_bounds__(256) void prep_kernel(
    const float* __restrict__ Wih, ushort* __restrict__ Wihp,
    const float* __restrict__ Whh, ushort* __restrict__ Whhp,
    const float* __restrict__ Wobs, ushort* __restrict__ WobsT,
    const float* __restrict__ W1, ushort* __restrict__ W1T,
    const float* __restrict__ W2, ushort* __restrict__ W2T,
    const float* __restrict__ Wa, const float* __restrict__ Wv,
    const float* __restrict__ ba, const float* __restrict__ bv,
    const float* __restrict__ bih, const float* __restrict__ bhh,
    ushort* __restrict__ WaTe, float* __restrict__ bias_ext, float* __restrict__ bias12,
    const float* __restrict__ ai1, const float* __restrict__ aj1,
    const float* __restrict__ ai2, const float* __restrict__ aj2,
    ushort* __restrict__ wab1, ushort* __restrict__ wab2)
{
  __shared__ float tile[32][33];
  const int bid = blockIdx.x;
  const int tid = threadIdx.x;
  if (bid < 512) {
    const int i = bid * 256 + tid;
    const int half = i >> 16;            // 0 = Wih, 1 = Whh
    const int ii = i & 65535;
    const int pr = ii >> 6, k4 = ii & 63;
    const int orow = ((pr >> 4) & 3) * 256 + (pr >> 6) * 16 + (pr & 15);
    const float* s = half ? Whh : Wih;
    ushort* d = half ? Whhp : Wihp;
    const float4 v = *(const float4*)(s + (size_t)orow * 256 + k4 * 4);
    ushort4 o; o.x = f2b(v.x); o.y = f2b(v.y); o.z = f2b(v.z); o.w = f2b(v.w);
    *(ushort4*)(d + (size_t)pr * 256 + k4 * 4) = o;
  } else if (bid < 704) {
    const int t = bid - 512;
    const int mat = t >> 6, sub = t & 63;
    const float* in = mat == 0 ? Wobs : (mat == 1 ? W1 : W2);
    ushort* outp = mat == 0 ? WobsT : (mat == 1 ? W1T : W2T);
    const int c0 = (sub & 7) * 32, r0 = (sub >> 3) * 32;
    const int tx = tid & 31, ty = tid >> 5;
    #pragma unroll
    for (int p = 0; p < 32; p += 8)
      tile[ty + p][tx] = in[(size_t)(r0 + ty + p) * 256 + c0 + tx];
    __syncthreads();
    #pragma unroll
    for (int p = 0; p < 32; p += 8)
      outp[(size_t)(c0 + ty + p) * 256 + r0 + tx] = f2b(tile[tx][ty + p]);
  } else if (bid < 965) {
    const int idx = (bid - 704) * 256 + tid;
    if (idx < 65536) {
      const int n = idx >> 9, k = idx & 511;
      const float v = n < 64 ? Wa[(size_t)k * 64 + n] : (n == 64 ? Wv[k] : 0.0f);
      WaTe[idx] = f2b(v);
    } else if (idx < 65536 + 128) {
      const int n = idx - 65536;
      bias_ext[n] = n < 64 ? ba[n] : (n == 64 ? bv[0] : 0.0f);
    } else if (idx < 65536 + 128 + 1024) {
      const int pc = idx - 65536 - 128;
      const int orow = ((pc >> 4) & 3) * 256 + (pc >> 6) * 16 + (pc & 15);
      bias12[pc] = bih[orow] + bhh[orow];
    }
  } else if (bid < 981) {
    // wab1[16][256]: c<4 -> W1^T ai1 head c ; c in [4,8) -> W1^T aj1 ; else 0
    const int c = bid - 965;
    const int k = tid;
    float val = 0.0f;
    if (c < 8) {
      const int h = c & 3;
      const float* av = (c < 4) ? ai1 : aj1;
      for (int g = 0; g < 64; ++g)
        val += W1[(size_t)k * 256 + h * 64 + g] * av[h * 64 + g];
    }
    wab1[c * 256 + k] = f2b(val);
  } else {
    // wab2[16][256]: c==0 -> W2^T ai2 ; c==1 -> W2^T aj2 ; else 0
    const int c = bid - 981;
    const int k = tid;
    float val = 0.0f;
    if (c < 2) {
      const float* av = (c == 0) ? ai2 : aj2;
      for (int g = 0; g < 256; ++g)
        val += W2[(size_t)k * 256 + g] * av[g];
    }
    wab2[c * 256 + k] = f2b(val);
  }
}

// ===== enc GEMM: enc_bf = bf16(obs @ WobsT^T + bobs); A fp32 converted in staging =====
__global__ __launch_bounds__(256) void enc_gemm(
    const float* __restrict__ obs, const ushort* __restrict__ WobsT,
    const float* __restrict__ bobs, ushort* __restrict__ enc_bf)
{
  constexpr int LDT = 40;
  __shared__ __align__(16) ushort As[64 * LDT];
  __shared__ __align__(16) ushort Bs[64 * LDT];
  const int tid = threadIdx.x;
  const int wave = tid >> 6, lane = tid & 63;
  const int wr = wave >> 1, wc = wave & 1;
  const int m0 = blockIdx.y * 64, n0 = blockIdx.x * 64;
  floatx4 acc[2][2] = {};
  const int r = tid >> 2, kq = tid & 3;
  const int lm = lane & 15, lq = lane >> 4;
  for (int k0 = 0; k0 < 256; k0 += 32) {
    {
      const float* s = &obs[(size_t)(m0 + r) * 256 + k0 + kq * 8];
      const float4 a = *(const float4*)s;
      const float4 b = *(const float4*)(s + 4);
      ushort4 o1, o2;
      o1.x = f2b(a.x); o1.y = f2b(a.y); o1.z = f2b(a.z); o1.w = f2b(a.w);
      o2.x = f2b(b.x); o2.y = f2b(b.y); o2.z = f2b(b.z); o2.w = f2b(b.w);
      *(ushort4*)&As[r * LDT + kq * 8] = o1;
      *(ushort4*)&As[r * LDT + kq * 8 + 4] = o2;
      *(float4*)&Bs[r * LDT + kq * 8] =
          *(const float4*)&WobsT[(size_t)(n0 + r) * 256 + k0 + kq * 8];
    }
    __syncthreads();
    short8 af[2], bfr[2];
    #pragma unroll
    for (int i = 0; i < 2; ++i)
      af[i] = *(const short8*)&As[(wr * 32 + i * 16 + lm) * LDT + lq * 8];
    #pragma unroll
    for (int j = 0; j < 2; ++j)
      bfr[j] = *(const short8*)&Bs[(wc * 32 + j * 16 + lm) * LDT + lq * 8];
    #pragma unroll
    for (int i = 0; i < 2; ++i)
      #pragma unroll
      for (int j = 0; j < 2; ++j)
        acc[i][j] = __builtin_amdgcn_mfma_f32_16x16x32_bf16(af[i], bfr[j], acc[i][j], 0, 0, 0);
    __syncthreads();
  }
  #pragma unroll
  for (int i = 0; i < 2; ++i)
    #pragma unroll
    for (int j = 0; j < 2; ++j) {
      const int col = n0 + wc * 32 + j * 16 + lm;
      const float badd = bobs[col];
      #pragma unroll
      for (int t = 0; t < 4; ++t) {
        const int row = m0 + wr * 32 + i * 16 + lq * 4 + t;
        enc_bf[(size_t)row * 256 + col] = f2b(acc[i][j][t] + badd);
      }
    }
}

// ===== fused gates GEMM (gate-permuted cols) + register LSTM + minmax =====
// BM=64, BN=64, BK=64: grid (16, 64) = 1024 blocks (4/CU); 8 barriers.
__global__ __launch_bounds__(256) void gates_lstm_kernel(
    const ushort* __restrict__ enc_bf, const ushort* __restrict__ Wihp,
    const float* __restrict__ h0, const ushort* __restrict__ Whhp,
    const float* __restrict__ bias12p, const float* __restrict__ c0,
    float* __restrict__ h_out, float* __restrict__ c_out, ushort* __restrict__ h_bf,
    float* __restrict__ pmn, float* __restrict__ pmx)
{
  constexpr int LDT = 72;   // 64 + 8 pad
  __shared__ __align__(16) ushort As[64 * LDT];
  __shared__ __align__(16) ushort Bs[64 * LDT];
  __shared__ float smn[4], smx[4];
  const int tid = threadIdx.x;
  const int wave = tid >> 6, lane = tid & 63;
  const int m0 = blockIdx.y * 64, n0 = blockIdx.x * 64;
  floatx4 acc[4] = {};
  const int r = tid >> 2, kq = tid & 3;
  const int lm = lane & 15, lq = lane >> 4;
  for (int k0 = 0; k0 < 512; k0 += 64) {
    const ushort* B = (k0 < 256) ? Wihp : Whhp;
    const int kk = (k0 < 256) ? k0 : k0 - 256;
    if (k0 < 256) {
      #pragma unroll
      for (int q = 0; q < 2; ++q)
        *(float4*)&As[r * LDT + kq * 16 + q * 8] =
            *(const float4*)&enc_bf[(size_t)(m0 + r) * 256 + kk + kq * 16 + q * 8];
    } else {
      #pragma unroll
      for (int q = 0; q < 2; ++q) {
        const float* s = &h0[(size_t)(m0 + r) * 256 + kk + kq * 16 + q * 8];
        const float4 a = *(const float4*)s;
        const float4 b = *(const float4*)(s + 4);
        ushort4 o1, o2;
        o1.x = f2b(a.x); o1.y = f2b(a.y); o1.z = f2b(a.z); o1.w = f2b(a.w);
        o2.x = f2b(b.x); o2.y = f2b(b.y); o2.z = f2b(b.z); o2.w = f2b(b.w);
        *(ushort4*)&As[r * LDT + kq * 16 + q * 8] = o1;
        *(ushort4*)&As[r * LDT + kq * 16 + q * 8 + 4] = o2;
      }
    }
    #pragma unroll
    for (int q = 0; q < 2; ++q)
      *(float4*)&Bs[r * LDT + kq * 16 + q * 8] =
          *(const float4*)&B[(size_t)(n0 + r) * 256 + kk + kq * 16 + q * 8];
    __syncthreads();
    #pragma unroll
    for (int ks = 0; ks < 2; ++ks) {
      const short8 af = *(const short8*)&As[(wave * 16 + lm) * LDT + ks * 32 + lq * 8];
      short8 bfr[4];
      #pragma unroll
      for (int j = 0; j < 4; ++j)
        bfr[j] = *(const short8*)&Bs[(j * 16 + lm) * LDT + ks * 32 + lq * 8];
      #pragma unroll
      for (int j = 0; j < 4; ++j)
        acc[j] = __builtin_amdgcn_mfma_f32_16x16x32_bf16(af, bfr[j], acc[j], 0, 0, 0);
    }
    __syncthreads();
  }
  // register LSTM epilogue: lane owns unit d = bx*16+lm, j = gate
  const int d = blockIdx.x * 16 + lm;
  float b4[4];
  #pragma unroll
  for (int j = 0; j < 4; ++j) b4[j] = bias12p[n0 + j * 16 + lm];
  float mnl = 3.0e38f, mxl = -3.0e38f;
  #pragma unroll
  for (int t = 0; t < 4; ++t) {
    const int row = m0 + wave * 16 + lq * 4 + t;
    const size_t off = (size_t)row * 256 + d;
    const float gi = acc[0][t] + b4[0];
    const float gf = acc[1][t] + b4[1];
    const float gg = acc[2][t] + b4[2];
    const float go = acc[3][t] + b4[3];
    const float cc = c0[off];
    const float si = 1.0f / (1.0f + expf(-gi));
    const float sf = 1.0f / (1.0f + expf(-gf));
    const float so = 1.0f / (1.0f + expf(-go));
    const float c2 = sf * cc + si * tanhf(gg);
    const float h2 = so * tanhf(c2);
    h_out[off] = h2;
    c_out[off] = c2;
    h_bf[off] = f2b(h2);
    mnl = fminf(mnl, h2); mxl = fmaxf(mxl, h2);
  }
  #pragma unroll
  for (int o = 32; o > 0; o >>= 1) {
    mnl = fminf(mnl, __shfl_xor(mnl, o));
    mxl = fmaxf(mxl, __shfl_xor(mxl, o));
  }
  if (lane == 0) { smn[wave] = mnl; smx[wave] = mxl; }
  __syncthreads();
  if (tid == 0) {
    const int bid = blockIdx.y * 16 + blockIdx.x;
    pmn[bid] = fminf(fminf(smn[0], smn[1]), fminf(smn[2], smn[3]));
    pmx[bid] = fmaxf(fmaxf(smx[0], smx[1]), fmaxf(smx[2], smx[3]));
  }
}

// === fake-quant (fused global min/max from partials) -> bf16 + loss partial ===
__global__ __launch_bounds__(256) void quant_kernel(
    const float4* __restrict__ x, ushort* __restrict__ q, int n4,
    const float* __restrict__ pmn, const float* __restrict__ pmx, int np,
    float* __restrict__ part)
{
  __shared__ float smn[4], smx[4], sl[4], bmn, bmx;
  float mn = 3.0e38f, mx = -3.0e38f;
  for (int i = threadIdx.x; i < np; i += 256) {
    mn = fminf(mn, pmn[i]); mx = fmaxf(mx, pmx[i]);
  }
  #pragma unroll
  for (int o = 32; o > 0; o >>= 1) {
    mn = fminf(mn, __shfl_xor(mn, o));
    mx = fmaxf(mx, __shfl_xor(mx, o));
  }
  if ((threadIdx.x & 63) == 0) { smn[threadIdx.x >> 6] = mn; smx[threadIdx.x >> 6] = mx; }
  __syncthreads();
  if (threadIdx.x == 0) {
    bmn = fminf(fminf(smn[0], smn[1]), fminf(smn[2], smn[3]));
    bmx = fmaxf(fmaxf(smx[0], smx[1]), fmaxf(smx[2], smx[3]));
  }
  __syncthreads();
  mn = bmn; mx = bmx;
  if (mn == mx) { mn -= 0.01f; mx += 0.01f; }
  const float scale = (mx - mn) / 255.0f;
  const float zp = rintf(-mn / scale);
  float lsum = 0.0f;
  for (int idx = blockIdx.x * 256 + threadIdx.x; idx < n4; idx += gridDim.x * 256) {
    const float4 t = x[idx];
    float d0, d1, d2, d3;
    { float qq = fminf(fmaxf(rintf(t.x / scale + zp), 0.0f), 255.0f);
      d0 = (qq - zp) * scale; lsum += log2f(510.0f * fabsf(d0) + 1.0f); }
    { float qq = fminf(fmaxf(rintf(t.y / scale + zp), 0.0f), 255.0f);
      d1 = (qq - zp) * scale; lsum += log2f(510.0f * fabsf(d1) + 1.0f); }
    { float qq = fminf(fmaxf(rintf(t.z / scale + zp), 0.0f), 255.0f);
      d2 = (qq - zp) * scale; lsum += log2f(510.0f * fabsf(d2) + 1.0f); }
    { float qq = fminf(fmaxf(rintf(t.w / scale + zp), 0.0f), 255.0f);
      d3 = (qq - zp) * scale; lsum += log2f(510.0f * fabsf(d3) + 1.0f); }
    ushort4 o; o.x = f2b(d0); o.y = f2b(d1); o.z = f2b(d2); o.w = f2b(d3);
    *(ushort4*)(q + (size_t)idx * 4) = o;
  }
  #pragma unroll
  for (int o = 32; o > 0; o >>= 1) lsum += __shfl_xor(lsum, o);
  if ((threadIdx.x & 63) == 0) sl[threadIdx.x >> 6] = lsum;
  __syncthreads();
  if (threadIdx.x == 0) part[blockIdx.x] = sl[0] + sl[1] + sl[2] + sl[3];
}

// ==== GAT features: blocks 0..255 = h GEMM (fp32 out), 256..319 = ci/cj MFMA ====
template<int HN>
__global__ __launch_bounds__(256) void gat_feat_kernel(
    const ushort* __restrict__ Aq, const ushort* __restrict__ WT,
    const ushort* __restrict__ wab,
    float* __restrict__ hout, float* __restrict__ ci, float* __restrict__ cj)
{
  constexpr int LDT = 40;
  __shared__ __align__(16) ushort As[64 * LDT];
  __shared__ __align__(16) ushort Bs[64 * LDT];
  const int bid = blockIdx.x;
  const int tid = threadIdx.x;
  const int wave = tid >> 6, lane = tid & 63;
  const int lm = lane & 15, lq = lane >> 4;
  const int r = tid >> 2, kq = tid & 3;
  if (bid < 256) {
    const int bx = bid & 3, by = bid >> 2;
    const int m0 = by * 64, n0 = bx * 64;
    const int wr = wave >> 1, wc = wave & 1;
    floatx4 acc[2][2] = {};
    for (int k0 = 0; k0 < 256; k0 += 32) {
      *(float4*)&As[r * LDT + kq * 8] =
          *(const float4*)&Aq[(size_t)(m0 + r) * 256 + k0 + kq * 8];
      *(float4*)&Bs[r * LDT + kq * 8] =
          *(const float4*)&WT[(size_t)(n0 + r) * 256 + k0 + kq * 8];
      __syncthreads();
      short8 af[2], bfr[2];
      #pragma unroll
      for (int i = 0; i < 2; ++i)
        af[i] = *(const short8*)&As[(wr * 32 + i * 16 + lm) * LDT + lq * 8];
      #pragma unroll
      for (int j = 0; j < 2; ++j)
        bfr[j] = *(const short8*)&Bs[(wc * 32 + j * 16 + lm) * LDT + lq * 8];
      #pragma unroll
      for (int i = 0; i < 2; ++i)
        #pragma unroll
        for (int j = 0; j < 2; ++j)
          acc[i][j] = __builtin_amdgcn_mfma_f32_16x16x32_bf16(af[i], bfr[j], acc[i][j], 0, 0, 0);
      __syncthreads();
    }
    #pragma unroll
    for (int i = 0; i < 2; ++i)
      #pragma unroll
      for (int j = 0; j < 2; ++j) {
        const int col = n0 + wc * 32 + j * 16 + lm;
        #pragma unroll
        for (int t = 0; t < 4; ++t) {
          const int row = m0 + wr * 32 + i * 16 + lq * 4 + t;
          hout[(size_t)row * 256 + col] = acc[i][j][t];
        }
      }
  } else {
    // ci/cj: [64 rows] x [16 cols] MFMA against wab
    const int m0 = (bid - 256) * 64;
    floatx4 acc = {0.f, 0.f, 0.f, 0.f};
    for (int k0 = 0; k0 < 256; k0 += 32) {
      *(float4*)&As[r * LDT + kq * 8] =
          *(const float4*)&Aq[(size_t)(m0 + r) * 256 + k0 + kq * 8];
      if (r < 16)
        *(float4*)&Bs[r * LDT + kq * 8] =
            *(const float4*)&wab[(size_t)r * 256 + k0 + kq * 8];
      __syncthreads();
      const short8 af = *(const short8*)&As[(wave * 16 + lm) * LDT + lq * 8];
      const short8 bf = *(const short8*)&Bs[lm * LDT + lq * 8];
      acc = __builtin_amdgcn_mfma_f32_16x16x32_bf16(af, bf, acc, 0, 0, 0);
      __syncthreads();
    }
    #pragma unroll
    for (int t = 0; t < 4; ++t) {
      const int row = m0 + wave * 16 + lq * 4 + t;
      if (lm < HN) ci[lm * 4096 + row] = acc[t];
      else if (lm < 2 * HN) cj[(lm - HN) * 4096 + row] = acc[t];
    }
  }
}

// ====== rank sort, u32 keys (top-20 value bits | 12-bit idx), b128 reads ======
__global__ __launch_bounds__(1024) void rank_sort_kernel(
    const float* __restrict__ c, unsigned* __restrict__ skey,
    float* __restrict__ sc, int* __restrict__ pm)
{
  __shared__ __align__(16) unsigned lk[4096];
  __shared__ int scnt[16][64];
  const int head = blockIdx.x >> 6;
  const int seg = blockIdx.x & 63;
  const float* ch = c + head * 4096;
  for (int idx = threadIdx.x; idx < 4096; idx += 1024)
    lk[idx] = (encf(ch[idx]) & 0xFFFFF000u) | (unsigned)idx;
  __syncthreads();
  const int jl = threadIdx.x & 63;
  const int kg = threadIdx.x >> 6;
  const unsigned my = lk[seg * 64 + jl];
  int cnt = 0;
  const uint4* lk4 = (const uint4*)lk;
  const int k40 = kg * 64;
  #pragma unroll 8
  for (int k4 = k40; k4 < k40 + 64; ++k4) {
    const uint4 kv = lk4[k4];
    cnt += (kv.x < my ? 1 : 0) + (kv.y < my ? 1 : 0)
         + (kv.z < my ? 1 : 0) + (kv.w < my ? 1 : 0);
  }
  scnt[kg][jl] = cnt;
  __syncthreads();
  if (threadIdx.x < 64) {
    int rank = 0;
    #pragma unroll
    for (int g = 0; g < 16; ++g) rank += scnt[g][threadIdx.x];
    const unsigned kk = lk[seg * 64 + threadIdx.x];
    const int jj = (int)(kk & 0xFFFu);
    skey[head * 4096 + rank] = kk;
    sc[head * 4096 + rank] = ch[jj];
    pm[head * 4096 + rank] = jj;
  }
}

// ======= local scan (GAT1): 2 waves/block, wave0=PV asc, wave1=PU desc =======
__global__ __launch_bounds__(128) void local_scan1(
    const float* __restrict__ h1, const float* __restrict__ sc, const int* __restrict__ pm,
    float* __restrict__ PUl, float* __restrict__ PVl,
    float* __restrict__ dUl, float* __restrict__ dVl,
    float* __restrict__ cku, float* __restrict__ ckv,
    float* __restrict__ ckus, float* __restrict__ ckvs)
{
  const int head = blockIdx.x >> 6;
  const int chunk = blockIdx.x & 63;
  const int wave = threadIdx.x >> 6;
  const int lane = threadIdx.x & 63;
  const float cmax = sc[head * 4096 + 4095];
  const int base = head * 4096 + chunk * 64;
  const float cv = sc[base + lane];
  const float u = expf(cv - cmax);
  const float v = expf(0.2f * (cv - cmax));
  const int myj = pm[base + lane];
  const float* hrow = h1 + head * 64 + lane;
  if (wave == 0) {
    float iu = u, iv = v;
    #pragma unroll
    for (int o = 1; o < 64; o <<= 1) {
      const float tu = __shfl_up(iu, o), tv = __shfl_up(iv, o);
      if (lane >= o) { iu += tu; iv += tv; }
    }
    const float totU = __shfl(iu, 63), totV = __shfl(iv, 63);
    dVl[base + lane] = iv - v;
    dUl[base + lane] = totU - (iu - u);
    if (lane == 0) { ckus[head * 64 + chunk] = totU; ckvs[head * 64 + chunk] = totV; }
    float accV = 0.f;
    #pragma unroll 16
    for (int k = 0; k < 64; ++k) {
      const float vk = __shfl(v, k);
      const int j = __shfl(myj, k);
      PVl[(size_t)(base + k) * 64 + lane] = accV;
      accV += vk * hrow[(size_t)j * 256];
    }
    ckv[(head * 64 + chunk) * 64 + lane] = accV;
  } else {
    float accU = 0.f;
    #pragma unroll 16
    for (int k = 63; k >= 0; --k) {
      const float uk = __shfl(u, k);
      const int j = __shfl(myj, k);
      accU += uk * hrow[(size_t)j * 256];
      PUl[(size_t)(base + k) * 64 + lane] = accU;
    }
    cku[(head * 64 + chunk) * 64 + lane] = accU;
  }
}

// === local scan (GAT2, g=256): grid (colgrp=2, chunk=64); waves 0-1 PV, 2-3 PU ===
__global__ __launch_bounds__(256) void local_scan2(
    const float* __restrict__ h2, const float* __restrict__ sc, const int* __restrict__ pm,
    float* __restrict__ PUl, float* __restrict__ PVl,
    float* __restrict__ dUl, float* __restrict__ dVl,
    float* __restrict__ cku, float* __restrict__ ckv,
    float* __restrict__ ckus, float* __restrict__ ckvs)
{
  __shared__ float su[64], sv[64];
  __shared__ int sj[64];
  const int chunk = blockIdx.y;
  const int colgrp = blockIdx.x;
  const int tid = threadIdx.x;
  const int wave = tid >> 6, lane = tid & 63;
  const float cmax = sc[4095];
  const int base = chunk * 64;
  if (tid < 64) {
    const float cv = sc[base + tid];
    const float u = expf(cv - cmax);
    const float v = expf(0.2f * (cv - cmax));
    su[tid] = u; sv[tid] = v; sj[tid] = pm[base + tid];
    if (colgrp == 0) {
      float iu = u, iv = v;
      #pragma unroll
      for (int o = 1; o < 64; o <<= 1) {
        const float tu = __shfl_up(iu, o), tv = __shfl_up(iv, o);
        if (lane >= o) { iu += tu; iv += tv; }
      }
      const float totU = __shfl(iu, 63), totV = __shfl(iv, 63);
      dVl[base + lane] = iv - v;
      dUl[base + lane] = totU - (iu - u);
      if (lane == 0) { ckus[chunk] = totU; ckvs[chunk] = totV; }
    }
  }
  __syncthreads();
  const int col = colgrp * 128 + (wave & 1) * 64 + lane;
  if (wave < 2) {
    float accV = 0.f;
    #pragma unroll 16
    for (int k = 0; k < 64; ++k) {
      PVl[(size_t)(base + k) * 256 + col] = accV;
      accV += sv[k] * h2[(size_t)sj[k] * 256 + col];
    }
    ckv[chunk * 256 + col] = accV;
  } else {
    float accU = 0.f;
    #pragma unroll 16
    for (int k = 63; k >= 0; --k) {
      accU += su[k] * h2[(size_t)sj[k] * 256 + col];
      PUl[(size_t)(base + k) * 256 + col] = accU;
    }
    cku[chunk * 256 + col] = accU;
  }
}

// ======= chunk prefix/suffix: lane=col (coalesced), serial chunk loop =======
__global__ __launch_bounds__(64) void prefix1_kernel(
    const float* __restrict__ cku, const float* __restrict__ ckv,
    const float* __restrict__ ckus, const float* __restrict__ ckvs,
    float* __restrict__ sufU, float* __restrict__ prefV,
    float* __restrict__ sufUs, float* __restrict__ prefVs)
{
  const int head = blockIdx.x, lane = threadIdx.x;
  float acc = 0.f;
  for (int c = 0; c < 64; ++c) {
    prefV[(head * 65 + c) * 64 + lane] = acc;
    acc += ckv[(head * 64 + c) * 64 + lane];
  }
  prefV[(head * 65 + 64) * 64 + lane] = acc;
  acc = 0.f;
  sufU[(head * 65 + 64) * 64 + lane] = 0.f;
  for (int c = 63; c >= 0; --c) {
    acc += cku[(head * 64 + c) * 64 + lane];
    sufU[(head * 65 + c) * 64 + lane] = acc;
  }
  {
    const float vs = ckvs[head * 64 + lane];
    const float us = ckus[head * 64 + lane];
    float iv = vs, iu = us;
    #pragma unroll
    for (int o = 1; o < 64; o <<= 1) {
      const float tv = __shfl_up(iv, o), tu = __shfl_up(iu, o);
      if (lane >= o) { iv += tv; iu += tu; }
    }
    prefVs[head * 65 + lane] = iv - vs;
    const float totU = __shfl(iu, 63);
    sufUs[head * 65 + lane] = totU - iu + us;
    if (lane == 63) {
      prefVs[head * 65 + 64] = iv;
      sufUs[head * 65 + 64] = 0.f;
    }
  }
}

__global__ __launch_bounds__(256) void prefix2_kernel(
    const float* __restrict__ cku, const float* __restrict__ ckv,
    const float* __restrict__ ckus, const float* __restrict__ ckvs,
    float* __restrict__ sufU, float* __restrict__ prefV,
    float* __restrict__ sufUs, float* __restrict__ prefVs)
{
  const int col = threadIdx.x;
  const int lane = col & 63;
  float acc = 0.f;
  for (int c = 0; c < 64; ++c) {
    prefV[c * 256 + col] = acc;
    acc += ckv[c * 256 + col];
  }
  prefV[64 * 256 + col] = acc;
  acc = 0.f;
  sufU[64 * 256 + col] = 0.f;
  for (int c = 63; c >= 0; --c) {
    acc += cku[c * 256 + col];
    sufU[c * 256 + col] = acc;
  }
  if (col < 64) {
    const float vs = ckvs[lane];
    const float us = ckus[lane];
    float iv = vs, iu = us;
    #pragma unroll
    for (int o = 1; o < 64; o <<= 1) {
      const float tv = __shfl_up(iv, o), tu = __shfl_up(iu, o);
      if (lane >= o) { iv += tv; iu += tu; }
    }
    prefVs[lane] = iv - vs;
    const float totU = __shfl(iu, 63);
    sufUs[lane] = totU - iu + us;
    if (lane == 63) { prefVs[64] = iv; sufUs[64] = 0.f; }
  }
}

// ====== GAT1 combine: lookup via u32-key binary search + minmax ======
__global__ __launch_bounds__(256) void combine1_kernel(
    const float* __restrict__ ci, const unsigned* __restrict__ skey,
    const float* __restrict__ sc,
    const float* __restrict__ sufU, const float* __restrict__ prefV,
    const float* __restrict__ sufUs, const float* __restrict__ prefVs,
    const float* __restrict__ PUl, const float* __restrict__ PVl,
    const float* __restrict__ dUl, const float* __restrict__ dVl,
    const float* __restrict__ b1, float* __restrict__ out,
    float* __restrict__ pmn, float* __restrict__ pmx)
{
  const int i = blockIdx.x;
  const int head = threadIdx.x >> 6;
  const int lane = threadIdx.x & 63;
  const unsigned* skh = skey + head * 4096;
  const float civ = ci[head * 4096 + i];
  const float cmax = sc[head * 4096 + 4095];
  const float sarg = civ + cmax;
  const float m = sarg > 0.f ? sarg : 0.2f * sarg;
  const float Af = expf(sarg - m);
  const float Bf = expf(0.2f * sarg - m);
  const unsigned tkey = (encf(-civ) & 0xFFFFF000u) | 0xFFFu;
  int lo = 0, hi = 4096;
  while (lo < hi) {
    const int mid = (lo + hi) >> 1;
    if (skh[mid] > tkey) hi = mid; else lo = mid + 1;
  }
  const int s = lo;
  float accP, accN, dP, dN;
  if (s == 4096) {
    accP = 0.f; dP = 0.f;
    accN = prefV[(head * 65 + 64) * 64 + lane];
    dN = prefVs[head * 65 + 64];
  } else {
    const int cs = s >> 6;
    accP = sufU[(head * 65 + cs + 1) * 64 + lane] + PUl[(size_t)(head * 4096 + s) * 64 + lane];
    accN = prefV[(head * 65 + cs) * 64 + lane] + PVl[(size_t)(head * 4096 + s) * 64 + lane];
    dP = sufUs[head * 65 + cs + 1] + dUl[head * 4096 + s];
    dN = prefVs[head * 65 + cs] + dVl[head * 4096 + s];
  }
  const float num = Af * accP + Bf * accN;
  const float den = Af * dP + Bf * dN;
  const float o = num / den + b1[head * 64 + lane];
  const float oe = o > 0.f ? o : expm1f(o);
  out[(size_t)i * 256 + head * 64 + lane] = oe;
  float mn = oe, mx = oe;
  #pragma unroll
  for (int of = 32; of > 0; of >>= 1) {
    mn = fminf(mn, __shfl_xor(mn, of));
    mx = fmaxf(mx, __shfl_xor(mx, of));
  }
  __shared__ float smn[4], smx[4];
  if (lane == 0) { smn[head] = mn; smx[head] = mx; }
  __syncthreads();
  if (threadIdx.x == 0) {
    pmn[i] = fminf(fminf(smn[0], smn[1]), fminf(smn[2], smn[3]));
    pmx[i] = fmaxf(fmaxf(smx[0], smx[1]), fmaxf(smx[2], smx[3]));
  }
}

// ========= GAT2 combine: lookup via u32-key search, writes bf16 =========
__global__ __launch_bounds__(256) void combine2_kernel(
    const float* __restrict__ ci, const unsigned* __restrict__ skey,
    const float* __restrict__ sc,
    const float* __restrict__ sufU, const float* __restrict__ prefV,
    const float* __restrict__ sufUs, const float* __restrict__ prefVs,
    const float* __restrict__ PUl, const float* __restrict__ PVl,
    const float* __restrict__ dUl, const float* __restrict__ dVl,
    const float* __restrict__ b2, ushort* __restrict__ outb)
{
  const int i = blockIdx.x;
  const int col = threadIdx.x;
  const float civ = ci[i];
  const float cmax = sc[4095];
  const float sarg = civ + cmax;
  const float m = sarg > 0.f ? sarg : 0.2f * sarg;
  const float Af = expf(sarg - m);
  const float Bf = expf(0.2f * sarg - m);
  const unsigned tkey = (encf(-civ) & 0xFFFFF000u) | 0xFFFu;
  int lo = 0, hi = 4096;
  while (lo < hi) {
    const int mid = (lo + hi) >> 1;
    if (skey[mid] > tkey) hi = mid; else lo = mid + 1;
  }
  const int s = lo;
  float accP, accN, dP, dN;
  if (s == 4096) {
    accP = 0.f; dP = 0.f;
    accN = prefV[64 * 256 + col];
    dN = prefVs[64];
  } else {
    const int cs = s >> 6;
    accP = sufU[(cs + 1) * 256 + col] + PUl[(size_t)s * 256 + col];
    accN = prefV[cs * 256 + col] + PVl[(size_t)s * 256 + col];
    dP = sufUs[cs + 1] + dUl[s];
    dN = prefVs[cs] + dVl[s];
  }
  const float num = Af * accP + Bf * accN;
  const float den = Af * dP + Bf * dN;
  outb[(size_t)i * 256 + col] = f2b(num / den + b2[col]);
}

// ==== heads: [h|comm2]@WaTe^T + bias, fused log-softmax + value + loss ====
__global__ __launch_bounds__(256) void heads_kernel(
    const ushort* __restrict__ h_bf, const ushort* __restrict__ comm2_bf,
    const ushort* __restrict__ WaTe, const float* __restrict__ bias_ext,
    float* __restrict__ out_logp, float* __restrict__ out_value,
    const float* __restrict__ p1, const float* __restrict__ p2,
    float* __restrict__ out_loss)
{
  constexpr int LDT = 40;
  __shared__ __align__(16) ushort As[64 * LDT];
  __shared__ __align__(16) ushort Bs[128 * LDT];
  __shared__ float lbuf[64][68];
  const int tid = threadIdx.x;
  const int wave = tid >> 6, lane = tid & 63;
  const int wr = wave >> 1, wc = wave & 1;
  const int m0 = blockIdx.x * 64;
  const int lm = lane & 15, lq = lane >> 4;
  floatx4 acc[2][4] = {};
  const int r = tid >> 2, kq = tid & 3;
  for (int k0 = 0; k0 < 512; k0 += 32) {
    const ushort* Asrc = (k0 < 256) ? h_bf : comm2_bf;
    const int kk = (k0 < 256) ? k0 : k0 - 256;
    *(float4*)&As[r * LDT + kq * 8] =
        *(const float4*)&Asrc[(size_t)(m0 + r) * 256 + kk + kq * 8];
    #pragma unroll
    for (int p = 0; p < 2; ++p) {
      const int rr = r + p * 64;
      *(float4*)&Bs[rr * LDT + kq * 8] =
          *(const float4*)&WaTe[(size_t)rr * 512 + k0 + kq * 8];
    }
    __syncthreads();
    short8 af[2], bfr[4];
    #pragma unroll
    for (int i = 0; i < 2; ++i)
      af[i] = *(const short8*)&As[(wr * 32 + i * 16 + lm) * LDT + lq * 8];
    #pragma unroll
    for (int j = 0; j < 4; ++j)
      bfr[j] = *(const short8*)&Bs[(wc * 64 + j * 16 + lm) * LDT + lq * 8];
    #pragma unroll
    for (int i = 0; i < 2; ++i)
      #pragma unroll
      for (int j = 0; j < 4; ++j)
        acc[i][j] = __builtin_amdgcn_mfma_f32_16x16x32_bf16(af[i], bfr[j], acc[i][j], 0, 0, 0);
    __syncthreads();
  }
  #pragma unroll
  for (int i = 0; i < 2; ++i)
    #pragma unroll
    for (int j = 0; j < 4; ++j) {
      const int col = wc * 64 + j * 16 + lm;
      if (col < 65) {
        const float badd = bias_ext[col];
        #pragma unroll
        for (int t = 0; t < 4; ++t)
          lbuf[wr * 32 + i * 16 + lq * 4 + t][col] = acc[i][j][t] + badd;
      }
    }
  __syncthreads();
  for (int rr2 = 0; rr2 < 16; ++rr2) {
    const int row = wave * 16 + rr2;
    const float x = lbuf[row][lane];
    float mx = x;
    #pragma unroll
    for (int o = 32; o > 0; o >>= 1) mx = fmaxf(mx, __shfl_xor(mx, o));
    float e = expf(x - mx);
    #pragma unroll
    for (int o = 32; o > 0; o >>= 1) e += __shfl_xor(e, o);
    out_logp[(size_t)(m0 + row) * 64 + lane] = x - mx - logf(e);
    if (lane == 0) out_value[m0 + row] = lbuf[row][64];
  }
  if (blockIdx.x == 0 && wave == 0) {
    float s = 0.f;
    #pragma unroll
    for (int k = 0; k < 4; ++k) s += p1[lane + k * 64] + p2[lane + k * 64];
    #pragma unroll
    for (int o = 32; o > 0; o >>= 1) s += __shfl_xor(s, o);
    if (lane == 0) out_loss[0] = s;
  }
}

// ============================ launch ============================
extern "C" void kernel_launch(void* const* d_in, const int* in_sizes, int n_in,
                              void* d_out, int out_size, void* d_ws, size_t ws_size,
                              hipStream_t stream) {
  const float* obs  = (const float*)d_in[0];
  const float* h0   = (const float*)d_in[1];
  const float* c0   = (const float*)d_in[2];
  const float* Wobs = (const float*)d_in[3];
  const float* bobs = (const float*)d_in[4];
  const float* Wih  = (const float*)d_in[5];
  const float* Whh  = (const float*)d_in[6];
  const float* bih  = (const float*)d_in[7];
  const float* bhh  = (const float*)d_in[8];
  const float* W1   = (const float*)d_in[9];
  const float* ai1  = (const float*)d_in[10];
  const float* aj1  = (const float*)d_in[11];
  const float* b1   = (const float*)d_in[12];
  const float* W2   = (const float*)d_in[13];
  const float* ai2  = (const float*)d_in[14];
  const float* aj2  = (const float*)d_in[15];
  const float* b2   = (const float*)d_in[16];
  const float* Wv   = (const float*)d_in[17];
  const float* bv   = (const float*)d_in[18];
  const float* Wa   = (const float*)d_in[19];
  const float* ba   = (const float*)d_in[20];

  float* out       = (float*)d_out;
  float* out_logp  = out;
  float* out_value = out + 262144;
  float* out_h     = out + 266240;
  float* out_c     = out + 1314816;
  float* out_loss  = out + 2363392;

  char* ws = (char*)d_ws;
  float* part1  = (float*)(ws + 256);
  float* part2  = (float*)(ws + 1280);
  float* pmn    = (float*)(ws + 2304);
  float* pmx    = (float*)(ws + 18688);
  const size_t MB = 1048576;
  const size_t base = 35072;
  ushort* Wihp    = (ushort*)(ws + base);
  ushort* Whhp    = (ushort*)(ws + base + 524288);
  ushort* WobsT   = (ushort*)(ws + base + 1 * MB);
  ushort* W1T     = (ushort*)(ws + base + 1 * MB + 131072);
  ushort* W2T     = (ushort*)(ws + base + 1 * MB + 262144);
  ushort* WaTe    = (ushort*)(ws + base + 1 * MB + 393216);
  float*  bias_ext= (float*) (ws + base + 1 * MB + 524288);
  float*  bias12  = (float*) (ws + base + 1 * MB + 525312);
  ushort* wab1    = (ushort*)(ws + base + 1 * MB + 532480);
  ushort* wab2    = (ushort*)(ws + base + 1 * MB + 540672);
  ushort* enc_bf  = (ushort*)(ws + base + 2 * MB);
  ushort* h_bf    = (ushort*)(ws + base + 4 * MB);
  ushort* comm_q1 = (ushort*)(ws + base + 6 * MB);
  ushort* comm_q2 = (ushort*)(ws + base + 8 * MB);
  ushort* comm2_bf= (ushort*)(ws + base + 10 * MB);
  float*  h1      = (float*) (ws + base + 12 * MB);
  float*  comm1e  = (float*) (ws + base + 16 * MB);
  float*  h2b     = (float*) (ws + base + 20 * MB);
  size_t so = base + 24 * MB;
  auto alloc = [&](size_t bytes) { size_t r = so; so += (bytes + 255) & ~255ull; return (char*)ws + r; };
  float* ci1    = (float*)alloc(4 * 4096 * 4);
  float* cj1    = (float*)alloc(4 * 4096 * 4);
  unsigned* skey1 = (unsigned*)alloc(4 * 4096 * 4);
  float* sc1    = (float*)alloc(4 * 4096 * 4);
  int*   pm1    = (int*)  alloc(4 * 4096 * 4);
  float* cku1   = (float*)alloc(4 * 64 * 64 * 4);
  float* ckv1   = (float*)alloc(4 * 64 * 64 * 4);
  float* ckus1  = (float*)alloc(4 * 64 * 4);
  float* ckvs1  = (float*)alloc(4 * 64 * 4);
  float* sufU1  = (float*)alloc(4 * 65 * 64 * 4);
  float* prefV1 = (float*)alloc(4 * 65 * 64 * 4);
  float* sufUs1 = (float*)alloc(4 * 65 * 4);
  float* prefVs1= (float*)alloc(4 * 65 * 4);
  float* ci2    = (float*)alloc(4096 * 4);
  float* cj2    = (float*)alloc(4096 * 4);
  unsigned* skey2 = (unsigned*)alloc(4096 * 4);
  float* sc2    = (float*)alloc(4096 * 4);
  int*   pm2    = (int*)  alloc(4096 * 4);
  float* cku2   = (float*)alloc(64 * 256 * 4);
  float* ckv2   = (float*)alloc(64 * 256 * 4);
  float* ckus2  = (float*)alloc(64 * 4);
  float* ckvs2  = (float*)alloc(64 * 4);
  float* sufU2  = (float*)alloc(65 * 256 * 4);
  float* prefV2 = (float*)alloc(65 * 256 * 4);
  float* sufUs2 = (float*)alloc(65 * 4);
  float* prefVs2= (float*)alloc(65 * 4);
  float* PUl    = (float*)alloc(4 * 4096 * 64 * 4);
  float* PVl    = (float*)alloc(4 * 4096 * 64 * 4);
  float* dUl    = (float*)alloc(4 * 4096 * 4);
  float* dVl    = (float*)alloc(4 * 4096 * 4);

  const dim3 b256(256);
  const int N4 = 262144;

  prep_kernel<<<dim3(997), b256, 0, stream>>>(
      Wih, Wihp, Whh, Whhp, Wobs, WobsT, W1, W1T, W2, W2T,
      Wa, Wv, ba, bv, bih, bhh, WaTe, bias_ext, bias12,
      ai1, aj1, ai2, aj2, wab1, wab2);
  enc_gemm<<<dim3(4, 64), b256, 0, stream>>>(obs, WobsT, bobs, enc_bf);
  gates_lstm_kernel<<<dim3(16, 64), b256, 0, stream>>>(
      enc_bf, Wihp, h0, Whhp, bias12, c0, out_h, out_c, h_bf, pmn, pmx);
  quant_kernel<<<dim3(256), b256, 0, stream>>>(
      (const float4*)out_h, comm_q1, N4, pmn, pmx, 1024, part1);
  // ---- GAT1 ----
  gat_feat_kernel<4><<<dim3(320), b256, 0, stream>>>(
      comm_q1, W1T, wab1, h1, ci1, cj1);
  rank_sort_kernel<<<dim3(256), dim3(1024), 0, stream>>>(cj1, skey1, sc1, pm1);
  local_scan1<<<dim3(256), dim3(128), 0, stream>>>(h1, sc1, pm1,
      PUl, PVl, dUl, dVl, cku1, ckv1, ckus1, ckvs1);
  prefix1_kernel<<<dim3(4), dim3(64), 0, stream>>>(cku1, ckv1, ckus1, ckvs1,
                                                   sufU1, prefV1, sufUs1, prefVs1);
  combine1_kernel<<<dim3(4096), b256, 0, stream>>>(ci1, skey1, sc1,
      sufU1, prefV1, sufUs1, prefVs1, PUl, PVl, dUl, dVl, b1, comm1e, pmn, pmx);
  quant_kernel<<<dim3(256), b256, 0, stream>>>(
      (const float4*)comm1e, comm_q2, N4, pmn, pmx, 4096, part2);
  // ---- GAT2 ----
  gat_feat_kernel<1><<<dim3(320), b256, 0, stream>>>(
      comm_q2, W2T, wab2, h2b, ci2, cj2);
  rank_sort_kernel<<<dim3(64), dim3(1024), 0, stream>>>(cj2, skey2, sc2, pm2);
  local_scan2<<<dim3(2, 64), b256, 0, stream>>>(h2b, sc2, pm2,
      PUl, PVl, dUl, dVl, cku2, ckv2, ckus2, ckvs2);
  prefix2_kernel<<<dim3(1), b256, 0, stream>>>(cku2, ckv2, ckus2, ckvs2,
                                               sufU2, prefV2, sufUs2, prefVs2);
  combine2_kernel<<<dim3(4096), b256, 0, stream>>>(ci2, skey2, sc2,
      sufU2, prefV2, sufUs2, prefVs2, PUl, PVl, dUl, dVl, b2, comm2_bf);
  // ---- heads (fused log-softmax + value + loss) ----
  heads_kernel<<<dim3(64), b256, 0, stream>>>(
      h_bf, comm2_bf, WaTe, bias_ext, out_logp, out_value, part1, part2, out_loss);
}